// Round 10
// baseline (221.278 us; speedup 1.0000x reference)
//
#include <hip/hip_runtime.h>
#include <hip/hip_bf16.h>

// Problem constants
#define HH   16
#define DD   64
#define HSZ  1024
#define BB   8
#define SS   1024
#define NTOK (BB*SS)   // 8192
#define LOG2E 1.4426950408889634f

typedef __attribute__((ext_vector_type(8))) short bf16x8;
typedef __attribute__((ext_vector_type(4))) float f32x4;
typedef unsigned short u16;
typedef __attribute__((ext_vector_type(4))) unsigned short u16x4;

__device__ __forceinline__ u16 bfc(float x) {
    __hip_bfloat16 h = __float2bfloat16(x);   // RNE; pairs into v_cvt_pk_bf16_f32
    return *(u16*)&h;
}

// 2^x via v_exp_f32 (native exp2). __exp2f is not declared on this toolchain.
__device__ __forceinline__ float exp2fast(float x) {
    return __builtin_amdgcn_exp2f(x);
}

// async global->LDS, 16B per lane. LDS dest is WAVE-UNIFORM base + lane*16;
// global src is per-lane (so gather through rmap is free).
__device__ __forceinline__ void gload16(const u16* g, u16* l) {
    __builtin_amdgcn_global_load_lds(
        (const __attribute__((address_space(1))) void*)g,
        (__attribute__((address_space(3))) void*)l, 16, 0, 0);
}

// ---------------------------------------------------------------------------
// Mask scan: per batch, rmap[b][j] = original row of the j-th UNMASKED key
// (mask==0 kept; reference maps mask==True -> -1e9 -> weight exactly 0 in f32).
// Pad entries [L,SS) point at row 0 (finite data; attn clamps key>=L anyway).
// Larr[b] = #kept. Mask format detected: int32 bool => bytes at idx%4!=0 zero.
// ---------------------------------------------------------------------------
__global__ __launch_bounds__(256) void mask_scan_kernel(const void* mask,
                                                        int* __restrict__ rmap,
                                                        int* __restrict__ Larr) {
    const int b   = blockIdx.x;
    const int tid = threadIdx.x;
    const unsigned char* mball = (const unsigned char*)mask;

    __shared__ int fmt_s;
    __shared__ int wtot[4];
    __shared__ int Ls;
    if (tid == 0) fmt_s = 0;
    __syncthreads();
    int nz = 0;
    for (int i = tid; i < BB * SS; i += 256)
        if ((i & 3) && mball[i]) nz = 1;
    if (nz) fmt_s = 1;          // benign race: all writers store 1
    __syncthreads();
    const int fmt = fmt_s;      // 1 = byte format

    const int base = tid * 4;
    int v[4];
#pragma unroll
    for (int e = 0; e < 4; ++e) {
        int val = fmt ? (int)mball[(size_t)b * SS + base + e]
                      : ((const int*)mask)[(size_t)b * SS + base + e];
        v[e] = (val == 0) ? 1 : 0;   // keep iff unmasked
    }
    int ts = v[0] + v[1] + v[2] + v[3];

    const int lane = tid & 63, wv = tid >> 6;
    int incl = ts;
#pragma unroll
    for (int d = 1; d < 64; d <<= 1) {
        int t = __shfl_up(incl, d);
        if (lane >= d) incl += t;
    }
    if (lane == 63) wtot[wv] = incl;
    __syncthreads();
    int woff = 0;
    for (int w = 0; w < wv; ++w) woff += wtot[w];
    int run = woff + incl - ts;   // exclusive prefix for this thread's first elem
#pragma unroll
    for (int e = 0; e < 4; ++e) {
        if (v[e]) rmap[(size_t)b * SS + run] = base + e;
        run += v[e];
    }
    if (tid == 0) { Ls = 0; }
    __syncthreads();
    if (tid == 0) {
        Ls = wtot[0] + wtot[1] + wtot[2] + wtot[3];
        Larr[b] = Ls;
    }
    __syncthreads();
    for (int j = Ls + tid; j < SS; j += 256) rmap[(size_t)b * SS + j] = 0;
}

// ---------------------------------------------------------------------------
// Triple-region f32 -> bf16 convert (8 elems/thread/iter, grid-stride).
// ---------------------------------------------------------------------------
__global__ __launch_bounds__(256) void cvt3_kernel(const float* __restrict__ s1,
                                                   u16* __restrict__ d1, int n1,
                                                   const float* __restrict__ s2,
                                                   u16* __restrict__ d2, int n2,
                                                   const float* __restrict__ s3,
                                                   u16* __restrict__ d3, int n3) {
    int i = blockIdx.x * blockDim.x + threadIdx.x;
    const int stride = gridDim.x * blockDim.x;
    const int ntot = n1 + n2 + n3;
    for (; i < ntot; i += stride) {
        const float* s; u16* d; int j;
        if (i < n1)           { s = s1; d = d1; j = i; }
        else if (i < n1 + n2) { s = s2; d = d2; j = i - n1; }
        else                  { s = s3; d = d3; j = i - n1 - n2; }
        f32x4 a = *(const f32x4*)&s[(size_t)j * 8];
        f32x4 b = *(const f32x4*)&s[(size_t)j * 8 + 4];
        union { bf16x8 v; u16 u[8]; } t;
#pragma unroll
        for (int e = 0; e < 4; ++e) { t.u[e] = bfc(a[e]); t.u[4 + e] = bfc(b[e]); }
        *(bf16x8*)&d[(size_t)j * 8] = t.v;
    }
}

// ---------------------------------------------------------------------------
// Projection GEMM: Y = X(bf16) @ W(bf16)^T + b.  BM=BN=128, BK=32, 4 waves.
// Both tiles staged via global_load_lds (m97 structure).
// MODE 0: Q -> bf16 [B,H,S,D], scaled by (1/8)*log2e  (all 8192 rows)
// MODE 1: K -> bf16 [B,H,Scomp,D]  GATHER: only unmasked rows, via rmap;
//         blocks past Lpad(b) exit. Output rows contiguous/compacted.
// MODE 2: V -> bf16 [B,H,D,Scomp]  (gather + transpose)
// MODE 3: ctx(bf16) @ Wo^T + bo -> f32 [B,S,HS] (d_out)
// ---------------------------------------------------------------------------
template<int MODE>
__global__ __launch_bounds__(256) void proj_kernel(const u16* __restrict__ X,
                                                   const u16* __restrict__ W,
                                                   const float* __restrict__ bias,
                                                   const int* __restrict__ rmap,
                                                   const int* __restrict__ Larr,
                                                   void* __restrict__ Yv) {
    const int bm = blockIdx.x;
    const int bn = blockIdx.y;
    const int tid  = threadIdx.x;
    const int wave = tid >> 6;
    const int lane = tid & 63;
    const int l15  = lane & 15;
    const int g    = lane >> 4;
    const int wr   = wave >> 1;
    const int wc   = wave & 1;

    const int b_   = bm >> 3;          // batch (MODE 1/2)
    const int row0 = (bm & 7) * 128;   // compacted row base (MODE 1/2)
    if constexpr (MODE == 1 || MODE == 2) {
        const int L = Larr[b_];
        const int Lpad = ((L + 127) >> 7) << 7;
        if (row0 >= Lpad) return;      // block fully in dead pad region
    }

    __shared__ u16 Xs[128 * 32];   // 8 KB, linear row-major (gload_lds dest)
    __shared__ u16 Ws[128 * 32];   // 8 KB

    f32x4 acc[4][4] = {};

    // staging geometry: lane covers 16B slot (wave*128+lane) and +64
    const int rA = (wave * 128 + lane) >> 2;        // row for issue 0 (0..127)
    const int rB = (wave * 128 + lane + 64) >> 2;   // row for issue 1
    const int c8 = (lane & 3) * 8;                  // k-subcolumn

    int xrA, xrB;   // global X row per issue
    if constexpr (MODE == 1 || MODE == 2) {
        xrA = (b_ << 10) + rmap[(size_t)b_ * SS + row0 + rA];
        xrB = (b_ << 10) + rmap[(size_t)b_ * SS + row0 + rB];
    } else {
        xrA = bm * 128 + rA;
        xrB = bm * 128 + rB;
    }

    for (int k0 = 0; k0 < HSZ; k0 += 32) {
        gload16(&X[(size_t)xrA * HSZ + k0 + c8], &Xs[(wave * 2 + 0) * 512]);
        gload16(&W[(size_t)(bn * 128 + rA) * HSZ + k0 + c8], &Ws[(wave * 2 + 0) * 512]);
        gload16(&X[(size_t)xrB * HSZ + k0 + c8], &Xs[(wave * 2 + 1) * 512]);
        gload16(&W[(size_t)(bn * 128 + rB) * HSZ + k0 + c8], &Ws[(wave * 2 + 1) * 512]);
        __syncthreads();   // implicit vmcnt(0) drain completes gloads

        bf16x8 a[4], bb[4];
#pragma unroll
        for (int m = 0; m < 4; ++m)
            a[m] = *(const bf16x8*)&Xs[(wr * 64 + m * 16 + l15) * 32 + g * 8];
#pragma unroll
        for (int n = 0; n < 4; ++n)
            bb[n] = *(const bf16x8*)&Ws[(wc * 64 + n * 16 + l15) * 32 + g * 8];
#pragma unroll
        for (int m = 0; m < 4; ++m)
#pragma unroll
            for (int n = 0; n < 4; ++n)
                acc[m][n] = __builtin_amdgcn_mfma_f32_16x16x32_bf16(a[m], bb[n], acc[m][n], 0, 0, 0);
        __syncthreads();
    }

    // ---- epilogue ----
#pragma unroll
    for (int m = 0; m < 4; ++m) {
#pragma unroll
        for (int n = 0; n < 4; ++n) {
            const int o = bn * 128 + wc * 64 + n * 16 + l15;
            const float bvv = bias[o];
            const int h_ = o >> 6, d = o & 63;
#pragma unroll
            for (int r = 0; r < 4; ++r) {
                const int lrow = wr * 64 + m * 16 + g * 4 + r;   // 0..127 in block
                float y = acc[m][n][r] + bvv;
                if constexpr (MODE == 0) {
                    const int nrow = bm * 128 + lrow;
                    int bb_ = nrow >> 10, s = nrow & 1023;
                    ((u16*)Yv)[(((size_t)bb_ * HH + h_) * SS + s) * DD + d] = bfc(y * (0.125f * LOG2E));
                } else if constexpr (MODE == 1) {
                    ((u16*)Yv)[(((size_t)b_ * HH + h_) * SS + row0 + lrow) * DD + d] = bfc(y);
                } else if constexpr (MODE == 2) {
                    ((u16*)Yv)[(((size_t)b_ * HH + h_) * DD + d) * SS + row0 + lrow] = bfc(y);
                } else {
                    const int nrow = bm * 128 + lrow;
                    ((float*)Yv)[(size_t)nrow * HSZ + (bn * 128 + wc * 64 + n * 16 + l15)] = y;
                }
            }
        }
    }
}

// ---------------------------------------------------------------------------
// Attention over COMPACTED keys (L = Larr[b]; no bias). Block = (128 queries,
// one (b,h)); 4 waves; each wave owns 32 queries (2 qq-tiles of 16), streams
// L keys in 64-chunks. Grid = 1024 blocks -> 4 blocks/CU for TLP (round 9 was
// grid-limited at 2/CU, occupancy 17.7%). Register footprint = round-3-proven
// shape: K double-buffered, V single per chunk (VGPR ~120). launch_bounds
// (256,2) is a guarantee, not a cap — occupancy rises with VGPR<=128.
// Swapped QK^T keeps scores lane-local (query = l15); tail chunks clamp
// s = (key < L) ? s : -3e38 BEFORE the max. Online softmax, defer-max, exp2.
// Pad keys [L,ceil64(L)) hold finite data (projected row 0) -> P=0 exactly.
// ---------------------------------------------------------------------------
__global__ __launch_bounds__(256, 2) void attn_kernel(const u16* __restrict__ Qh,
                                                      const u16* __restrict__ Kh,
                                                      const u16* __restrict__ Vt,
                                                      const int* __restrict__ Larr,
                                                      u16* __restrict__ ctx) {
    const int qt = blockIdx.x;   // 0..7
    const int h  = blockIdx.y;   // 0..15
    const int b  = blockIdx.z;   // 0..7
    const int bh = b * HH + h;

    const int tid  = threadIdx.x;
    const int wave = tid >> 6;
    const int lane = tid & 63;
    const int l15  = lane & 15;
    const int g    = lane >> 4;
    const int qw0  = qt * 128 + wave * 32;   // first query of this wave

    __shared__ u16 Pw[4][2][16][72];         // 18 KB; stride 72 -> 2-way banks (free)

    const u16* Qb = Qh + ((size_t)bh * SS + qw0) * DD;
    const u16* Kb = Kh + (size_t)bh * SS * DD;
    const u16* Vb = Vt + (size_t)bh * DD * SS;

    const int L = Larr[b];
    const int nchunks = (L + 63) >> 6;       // 64-key chunks (reads stay < ceil128(L))

    // Q fragments: qf[qq][half] = Q[qw0+qq*16+l15][half*32 + g*8 ..+8]
    bf16x8 qf[2][2];
#pragma unroll
    for (int qq = 0; qq < 2; ++qq)
#pragma unroll
        for (int hh = 0; hh < 2; ++hh)
            qf[qq][hh] = *(const bf16x8*)&Qb[(size_t)(qq * 16 + l15) * DD + hh * 32 + g * 8];

    f32x4 o[2][4] = {};                      // [qq][dt]; query = qq*16+g*4+r, d = dt*16+l15
    float mrun[2] = { -3e38f, -3e38f };
    float lrun[2] = { 0.0f, 0.0f };

    auto loadK = [&](bf16x8 (&kbX)[8], int c0) {
#pragma unroll
        for (int kt = 0; kt < 4; ++kt)
#pragma unroll
            for (int hh = 0; hh < 2; ++hh)
                kbX[kt * 2 + hh] =
                    *(const bf16x8*)&Kb[(size_t)(c0 + kt * 16 + l15) * DD + hh * 32 + g * 8];
    };
    auto loadV = [&](bf16x8 (&vbX)[8], int c0) {
#pragma unroll
        for (int dt = 0; dt < 4; ++dt)
#pragma unroll
            for (int kh = 0; kh < 2; ++kh)
                vbX[dt * 2 + kh] =
                    *(const bf16x8*)&Vb[(size_t)(dt * 16 + l15) * SS + c0 + kh * 32 + g * 8];
    };

    auto process = [&](const bf16x8 (&kbX)[8], const bf16x8 (&vbX)[8], int c0) {
#pragma unroll
        for (int qq = 0; qq < 2; ++qq) {
            // QK^T (swapped): s[kt][r] = score2(key c0+kt*16+g*4+r, query qw0+qq*16+l15)
            f32x4 s[4];
#pragma unroll
            for (int kt = 0; kt < 4; ++kt) {
                f32x4 a = {};
                a = __builtin_amdgcn_mfma_f32_16x16x32_bf16(kbX[kt * 2 + 0], qf[qq][0], a, 0, 0, 0);
                a = __builtin_amdgcn_mfma_f32_16x16x32_bf16(kbX[kt * 2 + 1], qf[qq][1], a, 0, 0, 0);
                s[kt] = a;
            }
            // tail clamp BEFORE the max (pad keys -> -3e38 -> P=0 exactly)
            if (c0 + 64 > L) {
#pragma unroll
                for (int kt = 0; kt < 4; ++kt) {
                    const int kid = c0 + kt * 16 + g * 4;
#pragma unroll
                    for (int r = 0; r < 4; ++r)
                        s[kt][r] = (kid + r < L) ? s[kt][r] : -3e38f;
                }
            }
            // chunk max (tree; per query l15)
            float pmk[4];
#pragma unroll
            for (int kt = 0; kt < 4; ++kt)
                pmk[kt] = fmaxf(fmaxf(s[kt][0], s[kt][1]), fmaxf(s[kt][2], s[kt][3]));
            float pm = fmaxf(fmaxf(pmk[0], pmk[1]), fmaxf(pmk[2], pmk[3]));
            pm = fmaxf(pm, __shfl_xor(pm, 16));
            pm = fmaxf(pm, __shfl_xor(pm, 32));

            // defer-max: rescale only when max grows past 8*log2e (wave-uniform)
            if (!__all(pm <= mrun[qq] + 11.5416f)) {
                float sc = exp2fast(mrun[qq] - pm);   // first chunk: exp2(-huge)=0
                mrun[qq] = pm;
                lrun[qq] *= sc;
                float f0 = __shfl(sc, g * 4 + 0);
                float f1 = __shfl(sc, g * 4 + 1);
                float f2 = __shfl(sc, g * 4 + 2);
                float f3 = __shfl(sc, g * 4 + 3);
#pragma unroll
                for (int dt = 0; dt < 4; ++dt) {
                    o[qq][dt][0] *= f0; o[qq][dt][1] *= f1;
                    o[qq][dt][2] *= f2; o[qq][dt][3] *= f3;
                }
            }

            // P~ = exp2(s - mrun) -> bf16 LDS (transpose to query-major), local sum
            float ls = 0.0f;
#pragma unroll
            for (int kt = 0; kt < 4; ++kt) {
                union { u16x4 v; u16 u[4]; } pv;
#pragma unroll
                for (int r = 0; r < 4; ++r) {
                    float e = exp2fast(s[kt][r] - mrun[qq]);
                    ls += e;
                    pv.u[r] = bfc(e);
                }
                *(u16x4*)&Pw[wave][qq & 1][l15][kt * 16 + g * 4] = pv.v;
            }
            ls += __shfl_xor(ls, 16);
            ls += __shfl_xor(ls, 32);
            lrun[qq] += ls;

            // PV: O[q][d] += P~ . V
#pragma unroll
            for (int kh = 0; kh < 2; ++kh) {
                bf16x8 pa = *(const bf16x8*)&Pw[wave][qq & 1][l15][kh * 32 + g * 8];
#pragma unroll
                for (int dt = 0; dt < 4; ++dt)
                    o[qq][dt] = __builtin_amdgcn_mfma_f32_16x16x32_bf16(pa, vbX[dt * 2 + kh], o[qq][dt], 0, 0, 0);
            }
        }
    };

    // chunk loop, pair-unrolled with static A/B buffers (no runtime-indexed frags)
    bf16x8 kbA[8], kbB[8];
    loadK(kbA, 0);
    int c = 0;
    while (c + 1 < nchunks) {
        bf16x8 vbA[8];
        loadV(vbA, c * 64);
        loadK(kbB, (c + 1) * 64);
        process(kbA, vbA, c * 64);
        bf16x8 vbB[8];
        loadV(vbB, (c + 1) * 64);
        loadK(kbA, ((c + 2 < nchunks) ? (c + 2) : (c + 1)) * 64);
        process(kbB, vbB, (c + 1) * 64);
        c += 2;
    }
    if (c < nchunks) {
        bf16x8 vbA[8];
        loadV(vbA, c * 64);
        process(kbA, vbA, c * 64);
    }

    // ---- epilogue: normalize per query, write ctx bf16 ----
#pragma unroll
    for (int qq = 0; qq < 2; ++qq) {
        float inv = 1.0f / lrun[qq];           // valid for query l15 (uniform over g)
        float i0 = __shfl(inv, g * 4 + 0);
        float i1 = __shfl(inv, g * 4 + 1);
        float i2 = __shfl(inv, g * 4 + 2);
        float i3 = __shfl(inv, g * 4 + 3);
#pragma unroll
        for (int dt = 0; dt < 4; ++dt) {
            const int col = h * DD + dt * 16 + l15;
            const int qr  = b * SS + qw0 + qq * 16 + g * 4;
            ctx[(size_t)(qr + 0) * HSZ + col] = bfc(o[qq][dt][0] * i0);
            ctx[(size_t)(qr + 1) * HSZ + col] = bfc(o[qq][dt][1] * i1);
            ctx[(size_t)(qr + 2) * HSZ + col] = bfc(o[qq][dt][2] * i2);
            ctx[(size_t)(qr + 3) * HSZ + col] = bfc(o[qq][dt][3] * i3);
        }
    }
}

// ---------------------------------------------------------------------------
extern "C" void kernel_launch(void* const* d_in, const int* in_sizes, int n_in,
                              void* d_out, int out_size, void* d_ws, size_t ws_size,
                              hipStream_t stream) {
    const float* v    = (const float*)d_in[0];
    const float* k    = (const float*)d_in[1];
    const float* q    = (const float*)d_in[2];
    const void*  mask = d_in[3];
    const float* Wq = (const float*)d_in[4];
    const float* bq = (const float*)d_in[5];
    const float* Wk = (const float*)d_in[6];
    const float* bk = (const float*)d_in[7];
    const float* Wv = (const float*)d_in[8];
    const float* bv = (const float*)d_in[9];
    const float* Wo = (const float*)d_in[10];
    const float* bo = (const float*)d_in[11];

    char* ws = (char*)d_ws;
    int*   rmap = (int*)ws;                         // 32 KB
    int*   Larr = (int*)(ws + 32768);               // 32 B
    u16*   wbf  = (u16*)(ws + 65536);               // 2 MB, reused Wq/Wk/Wv
    u16*   wbfo = (u16*)(ws + 65536 + 2097152);     // 2 MB, Wo
    u16*   xbf  = (u16*)(ws + 65536 + 2 * 2097152); // 16 MB, reused q/k/v, then ctx
    u16*   Qh   = xbf + (size_t)NTOK * HSZ;         // 16 MB each
    u16*   Kh   = Qh + (size_t)NTOK * HSZ;
    u16*   Vt   = Kh + (size_t)NTOK * HSZ;
    u16*   ctx  = xbf;                              // reuse (free after proj<2>)

    const int NX8 = NTOK * HSZ / 8;                 // 1048576
    const int NW8 = HSZ * HSZ / 8;                  // 131072

    mask_scan_kernel<<<BB, 256, 0, stream>>>(mask, rmap, Larr);

    dim3 pgrid(NTOK / 128, HSZ / 128);   // (64, 8)
    cvt3_kernel<<<2048, 256, 0, stream>>>(q, xbf, NX8, Wq, wbf, NW8,
                                          (const float*)nullptr, (u16*)nullptr, 0);
    proj_kernel<0><<<pgrid, 256, 0, stream>>>(xbf, wbf, bq, rmap, Larr, Qh);
    cvt3_kernel<<<2048, 256, 0, stream>>>(k, xbf, NX8, Wk, wbf, NW8,
                                          (const float*)nullptr, (u16*)nullptr, 0);
    proj_kernel<1><<<pgrid, 256, 0, stream>>>(xbf, wbf, bk, rmap, Larr, Kh);
    cvt3_kernel<<<2048, 256, 0, stream>>>(v, xbf, NX8, Wv, wbf, NW8, Wo, wbfo, NW8);
    proj_kernel<2><<<pgrid, 256, 0, stream>>>(xbf, wbf, bv, rmap, Larr, Vt);

    dim3 agrid(SS / 128, HH, BB);        // (8, 16, 8)
    attn_kernel<<<agrid, 256, 0, stream>>>(Qh, Kh, Vt, Larr, ctx);

    proj_kernel<3><<<pgrid, 256, 0, stream>>>(ctx, wbfo, bo, rmap, Larr, (float*)d_out);
}

// Round 11
// 218.045 us; speedup vs baseline: 1.0148x; 1.0148x over previous
//
#include <hip/hip_runtime.h>
#include <hip/hip_bf16.h>

// Problem constants
#define HH   16
#define DD   64
#define HSZ  1024
#define BB   8
#define SS   1024
#define NTOK (BB*SS)   // 8192
#define LOG2E 1.4426950408889634f

typedef __attribute__((ext_vector_type(8))) short bf16x8;
typedef __attribute__((ext_vector_type(4))) float f32x4;
typedef unsigned short u16;
typedef __attribute__((ext_vector_type(4))) unsigned short u16x4;

__device__ __forceinline__ u16 bfc(float x) {
    __hip_bfloat16 h = __float2bfloat16(x);   // RNE; pairs into v_cvt_pk_bf16_f32
    return *(u16*)&h;
}

// 2^x via v_exp_f32 (native exp2). __exp2f is not declared on this toolchain.
__device__ __forceinline__ float exp2fast(float x) {
    return __builtin_amdgcn_exp2f(x);
}

// async global->LDS, 16B per lane. LDS dest is WAVE-UNIFORM base + lane*16;
// global src is per-lane (so gather through rmap is free).
__device__ __forceinline__ void gload16(const u16* g, u16* l) {
    __builtin_amdgcn_global_load_lds(
        (const __attribute__((address_space(1))) void*)g,
        (__attribute__((address_space(3))) void*)l, 16, 0, 0);
}

// ---------------------------------------------------------------------------
// Mask scan: per batch, rmap[b][j] = original row of the j-th UNMASKED key
// (mask==0 kept; reference maps mask==True -> -1e9 -> weight exactly 0 in f32).
// Pad entries [L,SS) point at row 0 (finite data; attn clamps key>=L anyway).
// Larr[b] = #kept. Mask format detected: int32 bool => bytes at idx%4!=0 zero.
// ---------------------------------------------------------------------------
__global__ __launch_bounds__(256) void mask_scan_kernel(const void* mask,
                                                        int* __restrict__ rmap,
                                                        int* __restrict__ Larr) {
    const int b   = blockIdx.x;
    const int tid = threadIdx.x;
    const unsigned char* mball = (const unsigned char*)mask;

    __shared__ int fmt_s;
    __shared__ int wtot[4];
    __shared__ int Ls;
    if (tid == 0) fmt_s = 0;
    __syncthreads();
    int nz = 0;
    for (int i = tid; i < BB * SS; i += 256)
        if ((i & 3) && mball[i]) nz = 1;
    if (nz) fmt_s = 1;          // benign race: all writers store 1
    __syncthreads();
    const int fmt = fmt_s;      // 1 = byte format

    const int base = tid * 4;
    int v[4];
#pragma unroll
    for (int e = 0; e < 4; ++e) {
        int val = fmt ? (int)mball[(size_t)b * SS + base + e]
                      : ((const int*)mask)[(size_t)b * SS + base + e];
        v[e] = (val == 0) ? 1 : 0;   // keep iff unmasked
    }
    int ts = v[0] + v[1] + v[2] + v[3];

    const int lane = tid & 63, wv = tid >> 6;
    int incl = ts;
#pragma unroll
    for (int d = 1; d < 64; d <<= 1) {
        int t = __shfl_up(incl, d);
        if (lane >= d) incl += t;
    }
    if (lane == 63) wtot[wv] = incl;
    __syncthreads();
    int woff = 0;
    for (int w = 0; w < wv; ++w) woff += wtot[w];
    int run = woff + incl - ts;   // exclusive prefix for this thread's first elem
#pragma unroll
    for (int e = 0; e < 4; ++e) {
        if (v[e]) rmap[(size_t)b * SS + run] = base + e;
        run += v[e];
    }
    if (tid == 0) { Ls = 0; }
    __syncthreads();
    if (tid == 0) {
        Ls = wtot[0] + wtot[1] + wtot[2] + wtot[3];
        Larr[b] = Ls;
    }
    __syncthreads();
    for (int j = Ls + tid; j < SS; j += 256) rmap[(size_t)b * SS + j] = 0;
}

// ---------------------------------------------------------------------------
// Fused 7-region f32 -> bf16 convert (8 elems/thread/iter, grid-stride):
// q, k, v (8M elems each) + Wq, Wk, Wv, Wo (1M each). One launch, full BW.
// ---------------------------------------------------------------------------
__global__ __launch_bounds__(256) void cvt_all_kernel(
        const float* __restrict__ q,  u16* __restrict__ dq,
        const float* __restrict__ k,  u16* __restrict__ dk,
        const float* __restrict__ v,  u16* __restrict__ dv,
        const float* __restrict__ w0, u16* __restrict__ dw0,
        const float* __restrict__ w1, u16* __restrict__ dw1,
        const float* __restrict__ w2, u16* __restrict__ dw2,
        const float* __restrict__ w3, u16* __restrict__ dw3) {
    const int NX = NTOK * HSZ / 8;   // 1048576 units per input
    const int NW = HSZ * HSZ / 8;    // 131072 units per weight
    const int ntot = 3 * NX + 4 * NW;
    int i = blockIdx.x * blockDim.x + threadIdx.x;
    const int stride = gridDim.x * blockDim.x;
    for (; i < ntot; i += stride) {
        const float* s; u16* d; int j = i;
        if      (j < NX)            { s = q;  d = dq;  }
        else if ((j -= NX) < NX)    { s = k;  d = dk;  }
        else if ((j -= NX) < NX)    { s = v;  d = dv;  }
        else if ((j -= NX) < NW)    { s = w0; d = dw0; }
        else if ((j -= NW) < NW)    { s = w1; d = dw1; }
        else if ((j -= NW) < NW)    { s = w2; d = dw2; }
        else    { j -= NW;            s = w3; d = dw3; }
        f32x4 a = *(const f32x4*)&s[(size_t)j * 8];
        f32x4 b = *(const f32x4*)&s[(size_t)j * 8 + 4];
        union { bf16x8 v8; u16 u[8]; } t;
#pragma unroll
        for (int e = 0; e < 4; ++e) { t.u[e] = bfc(a[e]); t.u[4 + e] = bfc(b[e]); }
        *(bf16x8*)&d[(size_t)j * 8] = t.v8;
    }
}

// ---------------------------------------------------------------------------
// Projection GEMM: Y = X(bf16) @ W(bf16)^T + b.  BM=BN=128, BK=32, 4 waves.
// Both tiles staged via global_load_lds (m97 structure).
// MODE 0: Q -> bf16 [B,H,S,D], scaled by (1/8)*log2e  (all 8192 rows)
// MODE 1: K -> bf16 [B,H,Scomp,D]  GATHER: only unmasked rows, via rmap;
//         blocks past Lpad(b) exit. Output rows contiguous/compacted.
// MODE 2: V -> bf16 [B,H,D,Scomp]  (gather + transpose)
// MODE 3: ctx(bf16) @ Wo^T + bo -> f32 [B,S,HS] (d_out)
// ---------------------------------------------------------------------------
template<int MODE>
__global__ __launch_bounds__(256) void proj_kernel(const u16* __restrict__ X,
                                                   const u16* __restrict__ W,
                                                   const float* __restrict__ bias,
                                                   const int* __restrict__ rmap,
                                                   const int* __restrict__ Larr,
                                                   void* __restrict__ Yv) {
    const int bm = blockIdx.x;
    const int bn = blockIdx.y;
    const int tid  = threadIdx.x;
    const int wave = tid >> 6;
    const int lane = tid & 63;
    const int l15  = lane & 15;
    const int g    = lane >> 4;
    const int wr   = wave >> 1;
    const int wc   = wave & 1;

    const int b_   = bm >> 3;          // batch (MODE 1/2)
    const int row0 = (bm & 7) * 128;   // compacted row base (MODE 1/2)
    if constexpr (MODE == 1 || MODE == 2) {
        const int L = Larr[b_];
        const int Lpad = ((L + 127) >> 7) << 7;
        if (row0 >= Lpad) return;      // block fully in dead pad region
    }

    __shared__ u16 Xs[128 * 32];   // 8 KB, linear row-major (gload_lds dest)
    __shared__ u16 Ws[128 * 32];   // 8 KB

    f32x4 acc[4][4] = {};

    // staging geometry: lane covers 16B slot (wave*128+lane) and +64
    const int rA = (wave * 128 + lane) >> 2;        // row for issue 0 (0..127)
    const int rB = (wave * 128 + lane + 64) >> 2;   // row for issue 1
    const int c8 = (lane & 3) * 8;                  // k-subcolumn

    int xrA, xrB;   // global X row per issue
    if constexpr (MODE == 1 || MODE == 2) {
        xrA = (b_ << 10) + rmap[(size_t)b_ * SS + row0 + rA];
        xrB = (b_ << 10) + rmap[(size_t)b_ * SS + row0 + rB];
    } else {
        xrA = bm * 128 + rA;
        xrB = bm * 128 + rB;
    }

    for (int k0 = 0; k0 < HSZ; k0 += 32) {
        gload16(&X[(size_t)xrA * HSZ + k0 + c8], &Xs[(wave * 2 + 0) * 512]);
        gload16(&W[(size_t)(bn * 128 + rA) * HSZ + k0 + c8], &Ws[(wave * 2 + 0) * 512]);
        gload16(&X[(size_t)xrB * HSZ + k0 + c8], &Xs[(wave * 2 + 1) * 512]);
        gload16(&W[(size_t)(bn * 128 + rB) * HSZ + k0 + c8], &Ws[(wave * 2 + 1) * 512]);
        __syncthreads();   // implicit vmcnt(0) drain completes gloads

        bf16x8 a[4], bb[4];
#pragma unroll
        for (int m = 0; m < 4; ++m)
            a[m] = *(const bf16x8*)&Xs[(wr * 64 + m * 16 + l15) * 32 + g * 8];
#pragma unroll
        for (int n = 0; n < 4; ++n)
            bb[n] = *(const bf16x8*)&Ws[(wc * 64 + n * 16 + l15) * 32 + g * 8];
#pragma unroll
        for (int m = 0; m < 4; ++m)
#pragma unroll
            for (int n = 0; n < 4; ++n)
                acc[m][n] = __builtin_amdgcn_mfma_f32_16x16x32_bf16(a[m], bb[n], acc[m][n], 0, 0, 0);
        __syncthreads();
    }

    // ---- epilogue ----
#pragma unroll
    for (int m = 0; m < 4; ++m) {
#pragma unroll
        for (int n = 0; n < 4; ++n) {
            const int o = bn * 128 + wc * 64 + n * 16 + l15;
            const float bvv = bias[o];
            const int h_ = o >> 6, d = o & 63;
#pragma unroll
            for (int r = 0; r < 4; ++r) {
                const int lrow = wr * 64 + m * 16 + g * 4 + r;   // 0..127 in block
                float y = acc[m][n][r] + bvv;
                if constexpr (MODE == 0) {
                    const int nrow = bm * 128 + lrow;
                    int bb_ = nrow >> 10, s = nrow & 1023;
                    ((u16*)Yv)[(((size_t)bb_ * HH + h_) * SS + s) * DD + d] = bfc(y * (0.125f * LOG2E));
                } else if constexpr (MODE == 1) {
                    ((u16*)Yv)[(((size_t)b_ * HH + h_) * SS + row0 + lrow) * DD + d] = bfc(y);
                } else if constexpr (MODE == 2) {
                    ((u16*)Yv)[(((size_t)b_ * HH + h_) * DD + d) * SS + row0 + lrow] = bfc(y);
                } else {
                    const int nrow = bm * 128 + lrow;
                    ((float*)Yv)[(size_t)nrow * HSZ + (bn * 128 + wc * 64 + n * 16 + l15)] = y;
                }
            }
        }
    }
}

// ---------------------------------------------------------------------------
// Attention over COMPACTED keys (round-9 proven config: qq=4, 256 q/block,
// grid 512, __launch_bounds__(256,2), VGPR 128). Block = (256 queries, one
// (b,h)); 4 waves; each wave owns 64 queries (4 qq-tiles of 16), streams L
// keys in pairs of 64-chunks. Swapped QK^T keeps scores lane-local (query =
// l15); tail clamp BEFORE the max. Online softmax, defer-max, exp2.
// NEW: s_setprio(1) around MFMA clusters (T5) — waves here are barrier-free
// and independent, the regime where setprio measured +4-7% (m191).
// ---------------------------------------------------------------------------
__global__ __launch_bounds__(256, 2) void attn_kernel(const u16* __restrict__ Qh,
                                                      const u16* __restrict__ Kh,
                                                      const u16* __restrict__ Vt,
                                                      const int* __restrict__ Larr,
                                                      u16* __restrict__ ctx) {
    const int qt = blockIdx.x;   // 0..3
    const int h  = blockIdx.y;   // 0..15
    const int b  = blockIdx.z;   // 0..7
    const int bh = b * HH + h;

    const int tid  = threadIdx.x;
    const int wave = tid >> 6;
    const int lane = tid & 63;
    const int l15  = lane & 15;
    const int g    = lane >> 4;
    const int qw0  = qt * 256 + wave * 64;   // first query of this wave

    __shared__ u16 Pw[4][2][16][72];         // 18 KB; stride 72 -> 2-way banks (free)

    const u16* Qb = Qh + ((size_t)bh * SS + qw0) * DD;
    const u16* Kb = Kh + (size_t)bh * SS * DD;
    const u16* Vb = Vt + (size_t)bh * DD * SS;

    const int L = Larr[b];
    const int npairs = (L + 127) >> 7;

    // Q fragments: qf[qq][half] = Q[qw0+qq*16+l15][half*32 + g*8 ..+8]
    bf16x8 qf[4][2];
#pragma unroll
    for (int qq = 0; qq < 4; ++qq)
#pragma unroll
        for (int hh = 0; hh < 2; ++hh)
            qf[qq][hh] = *(const bf16x8*)&Qb[(size_t)(qq * 16 + l15) * DD + hh * 32 + g * 8];

    f32x4 o[4][4] = {};                      // [qq][dt]; query = qq*16+g*4+r, d = dt*16+l15
    float mrun[4] = { -3e38f, -3e38f, -3e38f, -3e38f };
    float lrun[4] = { 0.0f, 0.0f, 0.0f, 0.0f };

    auto loadK = [&](bf16x8 (&kbX)[8], int c0) {
#pragma unroll
        for (int kt = 0; kt < 4; ++kt)
#pragma unroll
            for (int hh = 0; hh < 2; ++hh)
                kbX[kt * 2 + hh] =
                    *(const bf16x8*)&Kb[(size_t)(c0 + kt * 16 + l15) * DD + hh * 32 + g * 8];
    };
    auto loadV = [&](bf16x8 (&vbX)[8], int c0) {
#pragma unroll
        for (int dt = 0; dt < 4; ++dt)
#pragma unroll
            for (int kh = 0; kh < 2; ++kh)
                vbX[dt * 2 + kh] =
                    *(const bf16x8*)&Vb[(size_t)(dt * 16 + l15) * SS + c0 + kh * 32 + g * 8];
    };

    auto process = [&](const bf16x8 (&kbX)[8], const bf16x8 (&vbX)[8], int c0) {
#pragma unroll
        for (int qq = 0; qq < 4; ++qq) {
            // QK^T (swapped): s[kt][r] = score2(key c0+kt*16+g*4+r, query qw0+qq*16+l15)
            f32x4 s[4];
            __builtin_amdgcn_s_setprio(1);
#pragma unroll
            for (int kt = 0; kt < 4; ++kt) {
                f32x4 a = {};
                a = __builtin_amdgcn_mfma_f32_16x16x32_bf16(kbX[kt * 2 + 0], qf[qq][0], a, 0, 0, 0);
                a = __builtin_amdgcn_mfma_f32_16x16x32_bf16(kbX[kt * 2 + 1], qf[qq][1], a, 0, 0, 0);
                s[kt] = a;
            }
            __builtin_amdgcn_s_setprio(0);
            // tail clamp BEFORE the max (pad keys -> -3e38 -> P=0 exactly)
            if (c0 + 64 > L) {
#pragma unroll
                for (int kt = 0; kt < 4; ++kt) {
                    const int kid = c0 + kt * 16 + g * 4;
#pragma unroll
                    for (int r = 0; r < 4; ++r)
                        s[kt][r] = (kid + r < L) ? s[kt][r] : -3e38f;
                }
            }
            // chunk max (tree; per query l15)
            float pmk[4];
#pragma unroll
            for (int kt = 0; kt < 4; ++kt)
                pmk[kt] = fmaxf(fmaxf(s[kt][0], s[kt][1]), fmaxf(s[kt][2], s[kt][3]));
            float pm = fmaxf(fmaxf(pmk[0], pmk[1]), fmaxf(pmk[2], pmk[3]));
            pm = fmaxf(pm, __shfl_xor(pm, 16));
            pm = fmaxf(pm, __shfl_xor(pm, 32));

            // defer-max: rescale only when max grows past 8*log2e (wave-uniform)
            if (!__all(pm <= mrun[qq] + 11.5416f)) {
                float sc = exp2fast(mrun[qq] - pm);   // first chunk: exp2(-huge)=0
                mrun[qq] = pm;
                lrun[qq] *= sc;
                float f0 = __shfl(sc, g * 4 + 0);
                float f1 = __shfl(sc, g * 4 + 1);
                float f2 = __shfl(sc, g * 4 + 2);
                float f3 = __shfl(sc, g * 4 + 3);
#pragma unroll
                for (int dt = 0; dt < 4; ++dt) {
                    o[qq][dt][0] *= f0; o[qq][dt][1] *= f1;
                    o[qq][dt][2] *= f2; o[qq][dt][3] *= f3;
                }
            }

            // P~ = exp2(s - mrun) -> bf16 LDS (transpose to query-major), local sum
            float ls = 0.0f;
#pragma unroll
            for (int kt = 0; kt < 4; ++kt) {
                union { u16x4 v; u16 u[4]; } pv;
#pragma unroll
                for (int r = 0; r < 4; ++r) {
                    float e = exp2fast(s[kt][r] - mrun[qq]);
                    ls += e;
                    pv.u[r] = bfc(e);
                }
                *(u16x4*)&Pw[wave][qq & 1][l15][kt * 16 + g * 4] = pv.v;
            }
            ls += __shfl_xor(ls, 16);
            ls += __shfl_xor(ls, 32);
            lrun[qq] += ls;

            // PV: O[q][d] += P~ . V
            __builtin_amdgcn_s_setprio(1);
#pragma unroll
            for (int kh = 0; kh < 2; ++kh) {
                bf16x8 pa = *(const bf16x8*)&Pw[wave][qq & 1][l15][kh * 32 + g * 8];
#pragma unroll
                for (int dt = 0; dt < 4; ++dt)
                    o[qq][dt] = __builtin_amdgcn_mfma_f32_16x16x32_bf16(pa, vbX[dt * 2 + kh], o[qq][dt], 0, 0, 0);
            }
            __builtin_amdgcn_s_setprio(0);
        }
    };

    bf16x8 kbA[8], kbB[8];
    loadK(kbA, 0);
    for (int t = 0; t < npairs; ++t) {
        const int cA = t * 128;
        bf16x8 vbA[8];
        loadV(vbA, cA);
        loadK(kbB, cA + 64);
        process(kbA, vbA, cA);
        bf16x8 vbB[8];
        loadV(vbB, cA + 64);
        loadK(kbA, (t + 1 < npairs) ? (t + 1) * 128 : cA);
        process(kbB, vbB, cA + 64);
    }

    // ---- epilogue: normalize per query, write ctx bf16 ----
#pragma unroll
    for (int qq = 0; qq < 4; ++qq) {
        float inv = 1.0f / lrun[qq];           // valid for query l15 (uniform over g)
        float i0 = __shfl(inv, g * 4 + 0);
        float i1 = __shfl(inv, g * 4 + 1);
        float i2 = __shfl(inv, g * 4 + 2);
        float i3 = __shfl(inv, g * 4 + 3);
#pragma unroll
        for (int dt = 0; dt < 4; ++dt) {
            const int col = h * DD + dt * 16 + l15;
            const int qr  = b * SS + qw0 + qq * 16 + g * 4;
            ctx[(size_t)(qr + 0) * HSZ + col] = bfc(o[qq][dt][0] * i0);
            ctx[(size_t)(qr + 1) * HSZ + col] = bfc(o[qq][dt][1] * i1);
            ctx[(size_t)(qr + 2) * HSZ + col] = bfc(o[qq][dt][2] * i2);
            ctx[(size_t)(qr + 3) * HSZ + col] = bfc(o[qq][dt][3] * i3);
        }
    }
}

// ---------------------------------------------------------------------------
extern "C" void kernel_launch(void* const* d_in, const int* in_sizes, int n_in,
                              void* d_out, int out_size, void* d_ws, size_t ws_size,
                              hipStream_t stream) {
    const float* v    = (const float*)d_in[0];
    const float* k    = (const float*)d_in[1];
    const float* q    = (const float*)d_in[2];
    const void*  mask = d_in[3];
    const float* Wq = (const float*)d_in[4];
    const float* bq = (const float*)d_in[5];
    const float* Wk = (const float*)d_in[6];
    const float* bk = (const float*)d_in[7];
    const float* Wv = (const float*)d_in[8];
    const float* bv = (const float*)d_in[9];
    const float* Wo = (const float*)d_in[10];
    const float* bo = (const float*)d_in[11];

    // d_out (32 MB f32, fully rewritten by the final proj<3>) doubles as
    // scratch for the q/k bf16 staging buffers before proj<3> runs.
    u16* qbf = (u16*)d_out;                         // 16 MB (dead after proj<0>)
    u16* kbf = qbf + (size_t)NTOK * HSZ;            // 16 MB (dead after proj<1>)

    char* ws = (char*)d_ws;
    int*   rmap = (int*)ws;                         // 32 KB
    int*   Larr = (int*)(ws + 32768);               // 32 B
    u16*   wqb  = (u16*)(ws + 65536);               // 2 MB each
    u16*   wkb  = wqb + (size_t)HSZ * HSZ;
    u16*   wvb  = wkb + (size_t)HSZ * HSZ;
    u16*   wob  = wvb + (size_t)HSZ * HSZ;
    u16*   vbf  = wob + (size_t)HSZ * HSZ;          // 16 MB (v bf16; ctx overlays)
    u16*   Qh   = vbf + (size_t)NTOK * HSZ;         // 16 MB each
    u16*   Kh   = Qh + (size_t)NTOK * HSZ;
    u16*   Vt   = Kh + (size_t)NTOK * HSZ;
    u16*   ctx  = vbf;                              // reuse (free after proj<2>)

    mask_scan_kernel<<<BB, 256, 0, stream>>>(mask, rmap, Larr);

    cvt_all_kernel<<<4096, 256, 0, stream>>>(q, qbf, k, kbf, v, vbf,
                                             Wq, wqb, Wk, wkb, Wv, wvb, Wo, wob);

    dim3 pgrid(NTOK / 128, HSZ / 128);   // (64, 8)
    proj_kernel<0><<<pgrid, 256, 0, stream>>>(qbf, wqb, bq, rmap, Larr, Qh);
    proj_kernel<1><<<pgrid, 256, 0, stream>>>(kbf, wkb, bk, rmap, Larr, Kh);
    proj_kernel<2><<<pgrid, 256, 0, stream>>>(vbf, wvb, bv, rmap, Larr, Vt);

    dim3 agrid(SS / 256, HH, BB);        // (4, 16, 8)
    attn_kernel<<<agrid, 256, 0, stream>>>(Qh, Kh, Vt, Larr, ctx);

    proj_kernel<3><<<pgrid, 256, 0, stream>>>(ctx, wob, bo, rmap, Larr, (float*)d_out);
}

// Round 12
// 205.370 us; speedup vs baseline: 1.0775x; 1.0617x over previous
//
#include <hip/hip_runtime.h>
#include <hip/hip_bf16.h>

// Problem constants
#define HH   16
#define DD   64
#define HSZ  1024
#define BB   8
#define SS   1024
#define NTOK (BB*SS)   // 8192
#define LOG2E 1.4426950408889634f

typedef __attribute__((ext_vector_type(8))) short bf16x8;
typedef __attribute__((ext_vector_type(4))) float f32x4;
typedef unsigned short u16;
typedef __attribute__((ext_vector_type(4))) unsigned short u16x4;

__device__ __forceinline__ u16 bfc(float x) {
    __hip_bfloat16 h = __float2bfloat16(x);   // RNE; pairs into v_cvt_pk_bf16_f32
    return *(u16*)&h;
}

// 2^x via v_exp_f32 (native exp2). __exp2f is not declared on this toolchain.
__device__ __forceinline__ float exp2fast(float x) {
    return __builtin_amdgcn_exp2f(x);
}

// async global->LDS, 16B per lane. LDS dest is WAVE-UNIFORM base + lane*16;
// global src is per-lane (so gather through rmap is free).
__device__ __forceinline__ void gload16(const u16* g, u16* l) {
    __builtin_amdgcn_global_load_lds(
        (const __attribute__((address_space(1))) void*)g,
        (__attribute__((address_space(3))) void*)l, 16, 0, 0);
}

// ---------------------------------------------------------------------------
// Mask scan: per batch, rmap[b][j] = original row of the j-th UNMASKED key
// (mask==0 kept; reference maps mask==True -> -1e9 -> weight exactly 0 in f32).
// Pad entries [L,SS) point at row 0 (finite data; attn clamps key>=L anyway).
// Larr[b] = #kept. Mask format detected: int32 bool => bytes at idx%4!=0 zero.
// ---------------------------------------------------------------------------
__global__ __launch_bounds__(256) void mask_scan_kernel(const void* mask,
                                                        int* __restrict__ rmap,
                                                        int* __restrict__ Larr) {
    const int b   = blockIdx.x;
    const int tid = threadIdx.x;
    const unsigned char* mball = (const unsigned char*)mask;

    __shared__ int fmt_s;
    __shared__ int wtot[4];
    __shared__ int Ls;
    if (tid == 0) fmt_s = 0;
    __syncthreads();
    int nz = 0;
    for (int i = tid; i < BB * SS; i += 256)
        if ((i & 3) && mball[i]) nz = 1;
    if (nz) fmt_s = 1;          // benign race: all writers store 1
    __syncthreads();
    const int fmt = fmt_s;      // 1 = byte format

    const int base = tid * 4;
    int v[4];
#pragma unroll
    for (int e = 0; e < 4; ++e) {
        int val = fmt ? (int)mball[(size_t)b * SS + base + e]
                      : ((const int*)mask)[(size_t)b * SS + base + e];
        v[e] = (val == 0) ? 1 : 0;   // keep iff unmasked
    }
    int ts = v[0] + v[1] + v[2] + v[3];

    const int lane = tid & 63, wv = tid >> 6;
    int incl = ts;
#pragma unroll
    for (int d = 1; d < 64; d <<= 1) {
        int t = __shfl_up(incl, d);
        if (lane >= d) incl += t;
    }
    if (lane == 63) wtot[wv] = incl;
    __syncthreads();
    int woff = 0;
    for (int w = 0; w < wv; ++w) woff += wtot[w];
    int run = woff + incl - ts;   // exclusive prefix for this thread's first elem
#pragma unroll
    for (int e = 0; e < 4; ++e) {
        if (v[e]) rmap[(size_t)b * SS + run] = base + e;
        run += v[e];
    }
    if (tid == 0) { Ls = 0; }
    __syncthreads();
    if (tid == 0) {
        Ls = wtot[0] + wtot[1] + wtot[2] + wtot[3];
        Larr[b] = Ls;
    }
    __syncthreads();
    for (int j = Ls + tid; j < SS; j += 256) rmap[(size_t)b * SS + j] = 0;
}

// ---------------------------------------------------------------------------
// Fused 7-region f32 -> bf16 convert (8 elems/thread/iter, grid-stride):
// q, k, v (8M elems each) + Wq, Wk, Wv, Wo (1M each). One launch, full BW.
// ---------------------------------------------------------------------------
__global__ __launch_bounds__(256) void cvt_all_kernel(
        const float* __restrict__ q,  u16* __restrict__ dq,
        const float* __restrict__ k,  u16* __restrict__ dk,
        const float* __restrict__ v,  u16* __restrict__ dv,
        const float* __restrict__ w0, u16* __restrict__ dw0,
        const float* __restrict__ w1, u16* __restrict__ dw1,
        const float* __restrict__ w2, u16* __restrict__ dw2,
        const float* __restrict__ w3, u16* __restrict__ dw3) {
    const int NX = NTOK * HSZ / 8;   // 1048576 units per input
    const int NW = HSZ * HSZ / 8;    // 131072 units per weight
    const int ntot = 3 * NX + 4 * NW;
    int i = blockIdx.x * blockDim.x + threadIdx.x;
    const int stride = gridDim.x * blockDim.x;
    for (; i < ntot; i += stride) {
        const float* s; u16* d; int j = i;
        if      (j < NX)            { s = q;  d = dq;  }
        else if ((j -= NX) < NX)    { s = k;  d = dk;  }
        else if ((j -= NX) < NX)    { s = v;  d = dv;  }
        else if ((j -= NX) < NW)    { s = w0; d = dw0; }
        else if ((j -= NW) < NW)    { s = w1; d = dw1; }
        else if ((j -= NW) < NW)    { s = w2; d = dw2; }
        else    { j -= NW;            s = w3; d = dw3; }
        f32x4 a = *(const f32x4*)&s[(size_t)j * 8];
        f32x4 b = *(const f32x4*)&s[(size_t)j * 8 + 4];
        union { bf16x8 v8; u16 u[8]; } t;
#pragma unroll
        for (int e = 0; e < 4; ++e) { t.u[e] = bfc(a[e]); t.u[4 + e] = bfc(b[e]); }
        *(bf16x8*)&d[(size_t)j * 8] = t.v8;
    }
}

// ---------------------------------------------------------------------------
// Projection GEMM: Y = X(bf16) @ W(bf16)^T + b.  BM=BN=128, BK=32, 4 waves.
// Both tiles staged via global_load_lds (m97 structure).
// MODE 0: Q -> bf16 [B,H,S,D], scaled by (1/8)*log2e  (all 8192 rows)
// MODE 1: K -> bf16 [B,H,Scomp,D]  GATHER: only unmasked rows, via rmap;
//         blocks past Lpad(b) exit. Output rows contiguous/compacted.
// MODE 2: V -> bf16 [B,H,D,Scomp]  (gather + transpose)
// MODE 3: ctx(bf16) @ Wo^T + bo -> f32 [B,S,HS] (d_out)
// ---------------------------------------------------------------------------
template<int MODE>
__global__ __launch_bounds__(256) void proj_kernel(const u16* __restrict__ X,
                                                   const u16* __restrict__ W,
                                                   const float* __restrict__ bias,
                                                   const int* __restrict__ rmap,
                                                   const int* __restrict__ Larr,
                                                   void* __restrict__ Yv) {
    const int bm = blockIdx.x;
    const int bn = blockIdx.y;
    const int tid  = threadIdx.x;
    const int wave = tid >> 6;
    const int lane = tid & 63;
    const int l15  = lane & 15;
    const int g    = lane >> 4;
    const int wr   = wave >> 1;
    const int wc   = wave & 1;

    const int b_   = bm >> 3;          // batch (MODE 1/2)
    const int row0 = (bm & 7) * 128;   // compacted row base (MODE 1/2)
    if constexpr (MODE == 1 || MODE == 2) {
        const int L = Larr[b_];
        const int Lpad = ((L + 127) >> 7) << 7;
        if (row0 >= Lpad) return;      // block fully in dead pad region
    }

    __shared__ u16 Xs[128 * 32];   // 8 KB, linear row-major (gload_lds dest)
    __shared__ u16 Ws[128 * 32];   // 8 KB

    f32x4 acc[4][4] = {};

    // staging geometry: lane covers 16B slot (wave*128+lane) and +64
    const int rA = (wave * 128 + lane) >> 2;        // row for issue 0 (0..127)
    const int rB = (wave * 128 + lane + 64) >> 2;   // row for issue 1
    const int c8 = (lane & 3) * 8;                  // k-subcolumn

    int xrA, xrB;   // global X row per issue
    if constexpr (MODE == 1 || MODE == 2) {
        xrA = (b_ << 10) + rmap[(size_t)b_ * SS + row0 + rA];
        xrB = (b_ << 10) + rmap[(size_t)b_ * SS + row0 + rB];
    } else {
        xrA = bm * 128 + rA;
        xrB = bm * 128 + rB;
    }

    for (int k0 = 0; k0 < HSZ; k0 += 32) {
        gload16(&X[(size_t)xrA * HSZ + k0 + c8], &Xs[(wave * 2 + 0) * 512]);
        gload16(&W[(size_t)(bn * 128 + rA) * HSZ + k0 + c8], &Ws[(wave * 2 + 0) * 512]);
        gload16(&X[(size_t)xrB * HSZ + k0 + c8], &Xs[(wave * 2 + 1) * 512]);
        gload16(&W[(size_t)(bn * 128 + rB) * HSZ + k0 + c8], &Ws[(wave * 2 + 1) * 512]);
        __syncthreads();   // implicit vmcnt(0) drain completes gloads

        bf16x8 a[4], bb[4];
#pragma unroll
        for (int m = 0; m < 4; ++m)
            a[m] = *(const bf16x8*)&Xs[(wr * 64 + m * 16 + l15) * 32 + g * 8];
#pragma unroll
        for (int n = 0; n < 4; ++n)
            bb[n] = *(const bf16x8*)&Ws[(wc * 64 + n * 16 + l15) * 32 + g * 8];
#pragma unroll
        for (int m = 0; m < 4; ++m)
#pragma unroll
            for (int n = 0; n < 4; ++n)
                acc[m][n] = __builtin_amdgcn_mfma_f32_16x16x32_bf16(a[m], bb[n], acc[m][n], 0, 0, 0);
        __syncthreads();
    }

    // ---- epilogue ----
#pragma unroll
    for (int m = 0; m < 4; ++m) {
#pragma unroll
        for (int n = 0; n < 4; ++n) {
            const int o = bn * 128 + wc * 64 + n * 16 + l15;
            const float bvv = bias[o];
            const int h_ = o >> 6, d = o & 63;
#pragma unroll
            for (int r = 0; r < 4; ++r) {
                const int lrow = wr * 64 + m * 16 + g * 4 + r;   // 0..127 in block
                float y = acc[m][n][r] + bvv;
                if constexpr (MODE == 0) {
                    const int nrow = bm * 128 + lrow;
                    int bb_ = nrow >> 10, s = nrow & 1023;
                    ((u16*)Yv)[(((size_t)bb_ * HH + h_) * SS + s) * DD + d] = bfc(y * (0.125f * LOG2E));
                } else if constexpr (MODE == 1) {
                    ((u16*)Yv)[(((size_t)b_ * HH + h_) * SS + row0 + lrow) * DD + d] = bfc(y);
                } else if constexpr (MODE == 2) {
                    ((u16*)Yv)[(((size_t)b_ * HH + h_) * DD + d) * SS + row0 + lrow] = bfc(y);
                } else {
                    const int nrow = bm * 128 + lrow;
                    ((float*)Yv)[(size_t)nrow * HSZ + (bn * 128 + wc * 64 + n * 16 + l15)] = y;
                }
            }
        }
    }
}

// ---------------------------------------------------------------------------
// Attention over COMPACTED keys (round-9 proven config: qq=4, 256 q/block,
// grid 512, __launch_bounds__(256,2), VGPR 128). Block = (256 queries, one
// (b,h)); 4 waves; each wave owns 64 queries (4 qq-tiles of 16), streams L
// keys in pairs of 64-chunks. Swapped QK^T keeps scores lane-local (query =
// l15); tail clamp BEFORE the max. Online softmax, defer-max, exp2.
// NOTE: s_setprio tested round 11: -10 µs (waves share the CU pipeline in
// lockstep-ish fashion; boosting MFMA waves starved co-resident loads). Out.
// ---------------------------------------------------------------------------
__global__ __launch_bounds__(256, 2) void attn_kernel(const u16* __restrict__ Qh,
                                                      const u16* __restrict__ Kh,
                                                      const u16* __restrict__ Vt,
                                                      const int* __restrict__ Larr,
                                                      u16* __restrict__ ctx) {
    const int qt = blockIdx.x;   // 0..3
    const int h  = blockIdx.y;   // 0..15
    const int b  = blockIdx.z;   // 0..7
    const int bh = b * HH + h;

    const int tid  = threadIdx.x;
    const int wave = tid >> 6;
    const int lane = tid & 63;
    const int l15  = lane & 15;
    const int g    = lane >> 4;
    const int qw0  = qt * 256 + wave * 64;   // first query of this wave

    __shared__ u16 Pw[4][2][16][72];         // 18 KB; stride 72 -> 2-way banks (free)

    const u16* Qb = Qh + ((size_t)bh * SS + qw0) * DD;
    const u16* Kb = Kh + (size_t)bh * SS * DD;
    const u16* Vb = Vt + (size_t)bh * DD * SS;

    const int L = Larr[b];
    const int npairs = (L + 127) >> 7;

    // Q fragments: qf[qq][half] = Q[qw0+qq*16+l15][half*32 + g*8 ..+8]
    bf16x8 qf[4][2];
#pragma unroll
    for (int qq = 0; qq < 4; ++qq)
#pragma unroll
        for (int hh = 0; hh < 2; ++hh)
            qf[qq][hh] = *(const bf16x8*)&Qb[(size_t)(qq * 16 + l15) * DD + hh * 32 + g * 8];

    f32x4 o[4][4] = {};                      // [qq][dt]; query = qq*16+g*4+r, d = dt*16+l15
    float mrun[4] = { -3e38f, -3e38f, -3e38f, -3e38f };
    float lrun[4] = { 0.0f, 0.0f, 0.0f, 0.0f };

    auto loadK = [&](bf16x8 (&kbX)[8], int c0) {
#pragma unroll
        for (int kt = 0; kt < 4; ++kt)
#pragma unroll
            for (int hh = 0; hh < 2; ++hh)
                kbX[kt * 2 + hh] =
                    *(const bf16x8*)&Kb[(size_t)(c0 + kt * 16 + l15) * DD + hh * 32 + g * 8];
    };
    auto loadV = [&](bf16x8 (&vbX)[8], int c0) {
#pragma unroll
        for (int dt = 0; dt < 4; ++dt)
#pragma unroll
            for (int kh = 0; kh < 2; ++kh)
                vbX[dt * 2 + kh] =
                    *(const bf16x8*)&Vb[(size_t)(dt * 16 + l15) * SS + c0 + kh * 32 + g * 8];
    };

    auto process = [&](const bf16x8 (&kbX)[8], const bf16x8 (&vbX)[8], int c0) {
#pragma unroll
        for (int qq = 0; qq < 4; ++qq) {
            // QK^T (swapped): s[kt][r] = score2(key c0+kt*16+g*4+r, query qw0+qq*16+l15)
            f32x4 s[4];
#pragma unroll
            for (int kt = 0; kt < 4; ++kt) {
                f32x4 a = {};
                a = __builtin_amdgcn_mfma_f32_16x16x32_bf16(kbX[kt * 2 + 0], qf[qq][0], a, 0, 0, 0);
                a = __builtin_amdgcn_mfma_f32_16x16x32_bf16(kbX[kt * 2 + 1], qf[qq][1], a, 0, 0, 0);
                s[kt] = a;
            }
            // tail clamp BEFORE the max (pad keys -> -3e38 -> P=0 exactly)
            if (c0 + 64 > L) {
#pragma unroll
                for (int kt = 0; kt < 4; ++kt) {
                    const int kid = c0 + kt * 16 + g * 4;
#pragma unroll
                    for (int r = 0; r < 4; ++r)
                        s[kt][r] = (kid + r < L) ? s[kt][r] : -3e38f;
                }
            }
            // chunk max (tree; per query l15)
            float pmk[4];
#pragma unroll
            for (int kt = 0; kt < 4; ++kt)
                pmk[kt] = fmaxf(fmaxf(s[kt][0], s[kt][1]), fmaxf(s[kt][2], s[kt][3]));
            float pm = fmaxf(fmaxf(pmk[0], pmk[1]), fmaxf(pmk[2], pmk[3]));
            pm = fmaxf(pm, __shfl_xor(pm, 16));
            pm = fmaxf(pm, __shfl_xor(pm, 32));

            // defer-max: rescale only when max grows past 8*log2e (wave-uniform)
            if (!__all(pm <= mrun[qq] + 11.5416f)) {
                float sc = exp2fast(mrun[qq] - pm);   // first chunk: exp2(-huge)=0
                mrun[qq] = pm;
                lrun[qq] *= sc;
                float f0 = __shfl(sc, g * 4 + 0);
                float f1 = __shfl(sc, g * 4 + 1);
                float f2 = __shfl(sc, g * 4 + 2);
                float f3 = __shfl(sc, g * 4 + 3);
#pragma unroll
                for (int dt = 0; dt < 4; ++dt) {
                    o[qq][dt][0] *= f0; o[qq][dt][1] *= f1;
                    o[qq][dt][2] *= f2; o[qq][dt][3] *= f3;
                }
            }

            // P~ = exp2(s - mrun) -> bf16 LDS (transpose to query-major), local sum
            float ls = 0.0f;
#pragma unroll
            for (int kt = 0; kt < 4; ++kt) {
                union { u16x4 v; u16 u[4]; } pv;
#pragma unroll
                for (int r = 0; r < 4; ++r) {
                    float e = exp2fast(s[kt][r] - mrun[qq]);
                    ls += e;
                    pv.u[r] = bfc(e);
                }
                *(u16x4*)&Pw[wave][qq & 1][l15][kt * 16 + g * 4] = pv.v;
            }
            ls += __shfl_xor(ls, 16);
            ls += __shfl_xor(ls, 32);
            lrun[qq] += ls;

            // PV: O[q][d] += P~ . V
#pragma unroll
            for (int kh = 0; kh < 2; ++kh) {
                bf16x8 pa = *(const bf16x8*)&Pw[wave][qq & 1][l15][kh * 32 + g * 8];
#pragma unroll
                for (int dt = 0; dt < 4; ++dt)
                    o[qq][dt] = __builtin_amdgcn_mfma_f32_16x16x32_bf16(pa, vbX[dt * 2 + kh], o[qq][dt], 0, 0, 0);
            }
        }
    };

    bf16x8 kbA[8], kbB[8];
    loadK(kbA, 0);
    for (int t = 0; t < npairs; ++t) {
        const int cA = t * 128;
        bf16x8 vbA[8];
        loadV(vbA, cA);
        loadK(kbB, cA + 64);
        process(kbA, vbA, cA);
        bf16x8 vbB[8];
        loadV(vbB, cA + 64);
        if (t + 1 < npairs) loadK(kbA, (t + 1) * 128);
        process(kbB, vbB, cA + 64);
    }

    // ---- epilogue: normalize per query, write ctx bf16 ----
#pragma unroll
    for (int qq = 0; qq < 4; ++qq) {
        float inv = 1.0f / lrun[qq];           // valid for query l15 (uniform over g)
        float i0 = __shfl(inv, g * 4 + 0);
        float i1 = __shfl(inv, g * 4 + 1);
        float i2 = __shfl(inv, g * 4 + 2);
        float i3 = __shfl(inv, g * 4 + 3);
#pragma unroll
        for (int dt = 0; dt < 4; ++dt) {
            const int col = h * DD + dt * 16 + l15;
            const int qr  = b * SS + qw0 + qq * 16 + g * 4;
            ctx[(size_t)(qr + 0) * HSZ + col] = bfc(o[qq][dt][0] * i0);
            ctx[(size_t)(qr + 1) * HSZ + col] = bfc(o[qq][dt][1] * i1);
            ctx[(size_t)(qr + 2) * HSZ + col] = bfc(o[qq][dt][2] * i2);
            ctx[(size_t)(qr + 3) * HSZ + col] = bfc(o[qq][dt][3] * i3);
        }
    }
}

// ---------------------------------------------------------------------------
extern "C" void kernel_launch(void* const* d_in, const int* in_sizes, int n_in,
                              void* d_out, int out_size, void* d_ws, size_t ws_size,
                              hipStream_t stream) {
    const float* v    = (const float*)d_in[0];
    const float* k    = (const float*)d_in[1];
    const float* q    = (const float*)d_in[2];
    const void*  mask = d_in[3];
    const float* Wq = (const float*)d_in[4];
    const float* bq = (const float*)d_in[5];
    const float* Wk = (const float*)d_in[6];
    const float* bk = (const float*)d_in[7];
    const float* Wv = (const float*)d_in[8];
    const float* bv = (const float*)d_in[9];
    const float* Wo = (const float*)d_in[10];
    const float* bo = (const float*)d_in[11];

    // d_out (32 MB f32, fully rewritten by the final proj<3>) doubles as
    // scratch for the q/k bf16 staging buffers before proj<3> runs.
    u16* qbf = (u16*)d_out;                         // 16 MB (dead after proj<0>)
    u16* kbf = qbf + (size_t)NTOK * HSZ;            // 16 MB (dead after proj<1>)

    char* ws = (char*)d_ws;
    int*   rmap = (int*)ws;                         // 32 KB
    int*   Larr = (int*)(ws + 32768);               // 32 B
    u16*   wqb  = (u16*)(ws + 65536);               // 2 MB each
    u16*   wkb  = wqb + (size_t)HSZ * HSZ;
    u16*   wvb  = wkb + (size_t)HSZ * HSZ;
    u16*   wob  = wvb + (size_t)HSZ * HSZ;
    u16*   vbf  = wob + (size_t)HSZ * HSZ;          // 16 MB (v bf16; ctx overlays)
    u16*   Qh   = vbf + (size_t)NTOK * HSZ;         // 16 MB each
    u16*   Kh   = Qh + (size_t)NTOK * HSZ;
    u16*   Vt   = Kh + (size_t)NTOK * HSZ;
    u16*   ctx  = vbf;                              // reuse (free after proj<2>)

    mask_scan_kernel<<<BB, 256, 0, stream>>>(mask, rmap, Larr);

    cvt_all_kernel<<<4096, 256, 0, stream>>>(q, qbf, k, kbf, v, vbf,
                                             Wq, wqb, Wk, wkb, Wv, wvb, Wo, wob);

    dim3 pgrid(NTOK / 128, HSZ / 128);   // (64, 8)
    proj_kernel<0><<<pgrid, 256, 0, stream>>>(qbf, wqb, bq, rmap, Larr, Qh);
    proj_kernel<1><<<pgrid, 256, 0, stream>>>(kbf, wkb, bk, rmap, Larr, Kh);
    proj_kernel<2><<<pgrid, 256, 0, stream>>>(vbf, wvb, bv, rmap, Larr, Vt);

    dim3 agrid(SS / 256, HH, BB);        // (4, 16, 8)
    attn_kernel<<<agrid, 256, 0, stream>>>(Qh, Kh, Vt, Larr, ctx);

    proj_kernel<3><<<pgrid, 256, 0, stream>>>(ctx, wob, bo, rmap, Larr, (float*)d_out);
}

// Round 13
// 194.080 us; speedup vs baseline: 1.1401x; 1.0582x over previous
//
#include <hip/hip_runtime.h>
#include <hip/hip_bf16.h>

// Problem constants
#define HH   16
#define DD   64
#define HSZ  1024
#define BB   8
#define SS   1024
#define NTOK (BB*SS)   // 8192
#define LOG2E 1.4426950408889634f
#define NCVTB 2048     // cvt blocks in the fused cvt+scan launch

typedef __attribute__((ext_vector_type(8))) short bf16x8;
typedef __attribute__((ext_vector_type(4))) float f32x4;
typedef unsigned short u16;
typedef __attribute__((ext_vector_type(4))) unsigned short u16x4;

__device__ __forceinline__ u16 bfc(float x) {
    __hip_bfloat16 h = __float2bfloat16(x);   // RNE; pairs into v_cvt_pk_bf16_f32
    return *(u16*)&h;
}

// 2^x via v_exp_f32 (native exp2). __exp2f is not declared on this toolchain.
__device__ __forceinline__ float exp2fast(float x) {
    return __builtin_amdgcn_exp2f(x);
}

// async global->LDS, 16B per lane. LDS dest is WAVE-UNIFORM base + lane*16;
// global src is per-lane (so gather through rmap is free).
__device__ __forceinline__ void gload16(const u16* g, u16* l) {
    __builtin_amdgcn_global_load_lds(
        (const __attribute__((address_space(1))) void*)g,
        (__attribute__((address_space(3))) void*)l, 16, 0, 0);
}

// ---------------------------------------------------------------------------
// Mask scan body (one 256-thread block per batch): rmap[b][j] = original row
// of the j-th UNMASKED key (mask==0 kept; reference maps mask==True -> -1e9
// -> weight exactly 0 in f32). Pad entries [L,SS) -> row 0 (finite data; attn
// clamps key>=L). Larr[b] = #kept. Mask format detected on-device: int32 bool
// => bytes at idx%4!=0 all zero.
// ---------------------------------------------------------------------------
__device__ __forceinline__ void mask_scan_body(const void* mask,
                                               int* __restrict__ rmap,
                                               int* __restrict__ Larr, int b) {
    const int tid = threadIdx.x;
    const unsigned char* mball = (const unsigned char*)mask;

    __shared__ int fmt_s;
    __shared__ int wtot[4];
    __shared__ int Ls;
    if (tid == 0) fmt_s = 0;
    __syncthreads();
    int nz = 0;
    for (int i = tid; i < BB * SS; i += 256)
        if ((i & 3) && mball[i]) nz = 1;
    if (nz) fmt_s = 1;          // benign race: all writers store 1
    __syncthreads();
    const int fmt = fmt_s;      // 1 = byte format

    const int base = tid * 4;
    int v[4];
#pragma unroll
    for (int e = 0; e < 4; ++e) {
        int val = fmt ? (int)mball[(size_t)b * SS + base + e]
                      : ((const int*)mask)[(size_t)b * SS + base + e];
        v[e] = (val == 0) ? 1 : 0;   // keep iff unmasked
    }
    int ts = v[0] + v[1] + v[2] + v[3];

    const int lane = tid & 63, wv = tid >> 6;
    int incl = ts;
#pragma unroll
    for (int d = 1; d < 64; d <<= 1) {
        int t = __shfl_up(incl, d);
        if (lane >= d) incl += t;
    }
    if (lane == 63) wtot[wv] = incl;
    __syncthreads();
    int woff = 0;
    for (int w = 0; w < wv; ++w) woff += wtot[w];
    int run = woff + incl - ts;   // exclusive prefix for this thread's first elem
#pragma unroll
    for (int e = 0; e < 4; ++e) {
        if (v[e]) rmap[(size_t)b * SS + run] = base + e;
        run += v[e];
    }
    __syncthreads();
    if (tid == 0) {
        Ls = wtot[0] + wtot[1] + wtot[2] + wtot[3];
        Larr[b] = Ls;
    }
    __syncthreads();
    for (int j = Ls + tid; j < SS; j += 256) rmap[(size_t)b * SS + j] = 0;
}

// ---------------------------------------------------------------------------
// Fused convert + mask scan. Blocks [0,NCVTB): grid-stride f32->bf16 over 7
// regions (q,k,v inputs + 4 weights). Blocks [NCVTB,NCVTB+BB): mask scan for
// batch (blockIdx.x - NCVTB). The 2 µs scan hides under the BW-bound convert.
// ---------------------------------------------------------------------------
__global__ __launch_bounds__(256) void cvt_scan_kernel(
        const float* __restrict__ q,  u16* __restrict__ dq,
        const float* __restrict__ k,  u16* __restrict__ dk,
        const float* __restrict__ v,  u16* __restrict__ dv,
        const float* __restrict__ w0, u16* __restrict__ dw0,
        const float* __restrict__ w1, u16* __restrict__ dw1,
        const float* __restrict__ w2, u16* __restrict__ dw2,
        const float* __restrict__ w3, u16* __restrict__ dw3,
        const void* mask, int* __restrict__ rmap, int* __restrict__ Larr) {
    if (blockIdx.x >= NCVTB) {
        mask_scan_body(mask, rmap, Larr, blockIdx.x - NCVTB);
        return;
    }
    const int NX = NTOK * HSZ / 8;   // 1048576 units per input
    const int NW = HSZ * HSZ / 8;    // 131072 units per weight
    const int ntot = 3 * NX + 4 * NW;
    int i = blockIdx.x * blockDim.x + threadIdx.x;
    const int stride = NCVTB * 256;
    for (; i < ntot; i += stride) {
        const float* s; u16* d; int j = i;
        if      (j < NX)            { s = q;  d = dq;  }
        else if ((j -= NX) < NX)    { s = k;  d = dk;  }
        else if ((j -= NX) < NX)    { s = v;  d = dv;  }
        else if ((j -= NX) < NW)    { s = w0; d = dw0; }
        else if ((j -= NW) < NW)    { s = w1; d = dw1; }
        else if ((j -= NW) < NW)    { s = w2; d = dw2; }
        else    { j -= NW;            s = w3; d = dw3; }
        f32x4 a = *(const f32x4*)&s[(size_t)j * 8];
        f32x4 b = *(const f32x4*)&s[(size_t)j * 8 + 4];
        union { bf16x8 v8; u16 u[8]; } t;
#pragma unroll
        for (int e = 0; e < 4; ++e) { t.u[e] = bfc(a[e]); t.u[4 + e] = bfc(b[e]); }
        *(bf16x8*)&d[(size_t)j * 8] = t.v8;
    }
}

// ---------------------------------------------------------------------------
// Projection GEMM body: Y = X(bf16) @ W(bf16)^T + b.  BM=BN=128, BK=32,
// 4 waves (2x2), 4x4 frags/wave; both tiles staged via global_load_lds (m97).
// MODE 0: Q -> bf16 [B,H,S,D], scaled by (1/8)*log2e  (all 8192 rows)
// MODE 1: K -> bf16 [B,H,Scomp,D]  gather via rmap, compacted output
// MODE 2: V -> bf16 [B,H,D,Scomp]  gather + transpose
// MODE 3: ctx(bf16) @ Wo^T + bo -> f32 [B,S,HS] (d_out)
// ---------------------------------------------------------------------------
template<int MODE>
__device__ __forceinline__ void proj_body(const u16* __restrict__ X,
                                          const u16* __restrict__ W,
                                          const float* __restrict__ bias,
                                          const int* __restrict__ rmap,
                                          const int* __restrict__ Larr,
                                          void* __restrict__ Yv,
                                          u16* Xs, u16* Ws) {
    const int bm = blockIdx.x;
    const int bn = blockIdx.y;
    const int tid  = threadIdx.x;
    const int wave = tid >> 6;
    const int lane = tid & 63;
    const int l15  = lane & 15;
    const int g    = lane >> 4;
    const int wr   = wave >> 1;
    const int wc   = wave & 1;

    const int b_   = bm >> 3;          // batch (MODE 1/2)
    const int row0 = (bm & 7) * 128;   // compacted row base (MODE 1/2)
    if constexpr (MODE == 1 || MODE == 2) {
        const int L = Larr[b_];
        const int Lpad = ((L + 127) >> 7) << 7;
        if (row0 >= Lpad) return;      // block fully in dead pad region
    }

    f32x4 acc[4][4] = {};

    // staging geometry: lane covers 16B slot (wave*128+lane) and +64
    const int rA = (wave * 128 + lane) >> 2;        // row for issue 0 (0..127)
    const int rB = (wave * 128 + lane + 64) >> 2;   // row for issue 1
    const int c8 = (lane & 3) * 8;                  // k-subcolumn

    int xrA, xrB;   // global X row per issue
    if constexpr (MODE == 1 || MODE == 2) {
        xrA = (b_ << 10) + rmap[(size_t)b_ * SS + row0 + rA];
        xrB = (b_ << 10) + rmap[(size_t)b_ * SS + row0 + rB];
    } else {
        xrA = bm * 128 + rA;
        xrB = bm * 128 + rB;
    }

    for (int k0 = 0; k0 < HSZ; k0 += 32) {
        gload16(&X[(size_t)xrA * HSZ + k0 + c8], &Xs[(wave * 2 + 0) * 512]);
        gload16(&W[(size_t)(bn * 128 + rA) * HSZ + k0 + c8], &Ws[(wave * 2 + 0) * 512]);
        gload16(&X[(size_t)xrB * HSZ + k0 + c8], &Xs[(wave * 2 + 1) * 512]);
        gload16(&W[(size_t)(bn * 128 + rB) * HSZ + k0 + c8], &Ws[(wave * 2 + 1) * 512]);
        __syncthreads();   // implicit vmcnt(0) drain completes gloads

        bf16x8 a[4], bb[4];
#pragma unroll
        for (int m = 0; m < 4; ++m)
            a[m] = *(const bf16x8*)&Xs[(size_t)(wr * 64 + m * 16 + l15) * 32 + g * 8];
#pragma unroll
        for (int n = 0; n < 4; ++n)
            bb[n] = *(const bf16x8*)&Ws[(size_t)(wc * 64 + n * 16 + l15) * 32 + g * 8];
#pragma unroll
        for (int m = 0; m < 4; ++m)
#pragma unroll
            for (int n = 0; n < 4; ++n)
                acc[m][n] = __builtin_amdgcn_mfma_f32_16x16x32_bf16(a[m], bb[n], acc[m][n], 0, 0, 0);
        __syncthreads();
    }

    // ---- epilogue ----
#pragma unroll
    for (int m = 0; m < 4; ++m) {
#pragma unroll
        for (int n = 0; n < 4; ++n) {
            const int o = bn * 128 + wc * 64 + n * 16 + l15;
            const float bvv = bias[o];
            const int h_ = o >> 6, d = o & 63;
#pragma unroll
            for (int r = 0; r < 4; ++r) {
                const int lrow = wr * 64 + m * 16 + g * 4 + r;   // 0..127 in block
                float y = acc[m][n][r] + bvv;
                if constexpr (MODE == 0) {
                    const int nrow = bm * 128 + lrow;
                    int bb_ = nrow >> 10, s = nrow & 1023;
                    ((u16*)Yv)[(((size_t)bb_ * HH + h_) * SS + s) * DD + d] = bfc(y * (0.125f * LOG2E));
                } else if constexpr (MODE == 1) {
                    ((u16*)Yv)[(((size_t)b_ * HH + h_) * SS + row0 + lrow) * DD + d] = bfc(y);
                } else if constexpr (MODE == 2) {
                    ((u16*)Yv)[(((size_t)b_ * HH + h_) * DD + d) * SS + row0 + lrow] = bfc(y);
                } else {
                    const int nrow = bm * 128 + lrow;
                    ((float*)Yv)[(size_t)nrow * HSZ + o] = y;
                }
            }
        }
    }
}

// Fused Q/K/V projection: blockIdx.z selects the projection. Packing all
// three into one launch fills CUs through proj<1>/<2>'s ~45% early-exit
// blocks (standalone they ran at ~1 active block/CU) and removes 2 gaps.
__global__ __launch_bounds__(256) void proj_qkv_kernel(
        const u16* __restrict__ qbf, const u16* __restrict__ wqb,
        const float* __restrict__ bq, u16* __restrict__ Qh,
        const u16* __restrict__ kbf, const u16* __restrict__ wkb,
        const float* __restrict__ bk, u16* __restrict__ Kh,
        const u16* __restrict__ vbf, const u16* __restrict__ wvb,
        const float* __restrict__ bv, u16* __restrict__ Vt,
        const int* __restrict__ rmap, const int* __restrict__ Larr) {
    __shared__ u16 Xs[128 * 32];   // 8 KB, linear row-major (gload_lds dest)
    __shared__ u16 Ws[128 * 32];   // 8 KB
    if (blockIdx.z == 0)      proj_body<0>(qbf, wqb, bq, rmap, Larr, Qh, Xs, Ws);
    else if (blockIdx.z == 1) proj_body<1>(kbf, wkb, bk, rmap, Larr, Kh, Xs, Ws);
    else                      proj_body<2>(vbf, wvb, bv, rmap, Larr, Vt, Xs, Ws);
}

__global__ __launch_bounds__(256) void proj_o_kernel(
        const u16* __restrict__ X, const u16* __restrict__ W,
        const float* __restrict__ bias, const int* __restrict__ rmap,
        const int* __restrict__ Larr, float* __restrict__ out) {
    __shared__ u16 Xs[128 * 32];
    __shared__ u16 Ws[128 * 32];
    proj_body<3>(X, W, bias, rmap, Larr, out, Xs, Ws);
}

// ---------------------------------------------------------------------------
// Attention over COMPACTED keys (round-12 proven config, UNCHANGED: qq=4,
// 256 q/block, grid 512, __launch_bounds__(256,2), VGPR 128, 63.5 µs).
// Swapped QK^T keeps scores lane-local (query = l15); tail clamp BEFORE the
// max. Online softmax, defer-max, exp2. s_setprio tested r11: -10 µs, out.
// ---------------------------------------------------------------------------
__global__ __launch_bounds__(256, 2) void attn_kernel(const u16* __restrict__ Qh,
                                                      const u16* __restrict__ Kh,
                                                      const u16* __restrict__ Vt,
                                                      const int* __restrict__ Larr,
                                                      u16* __restrict__ ctx) {
    const int qt = blockIdx.x;   // 0..3
    const int h  = blockIdx.y;   // 0..15
    const int b  = blockIdx.z;   // 0..7
    const int bh = b * HH + h;

    const int tid  = threadIdx.x;
    const int wave = tid >> 6;
    const int lane = tid & 63;
    const int l15  = lane & 15;
    const int g    = lane >> 4;
    const int qw0  = qt * 256 + wave * 64;   // first query of this wave

    __shared__ u16 Pw[4][2][16][72];         // 18 KB; stride 72 -> 2-way banks (free)

    const u16* Qb = Qh + ((size_t)bh * SS + qw0) * DD;
    const u16* Kb = Kh + (size_t)bh * SS * DD;
    const u16* Vb = Vt + (size_t)bh * DD * SS;

    const int L = Larr[b];
    const int npairs = (L + 127) >> 7;

    // Q fragments: qf[qq][half] = Q[qw0+qq*16+l15][half*32 + g*8 ..+8]
    bf16x8 qf[4][2];
#pragma unroll
    for (int qq = 0; qq < 4; ++qq)
#pragma unroll
        for (int hh = 0; hh < 2; ++hh)
            qf[qq][hh] = *(const bf16x8*)&Qb[(size_t)(qq * 16 + l15) * DD + hh * 32 + g * 8];

    f32x4 o[4][4] = {};                      // [qq][dt]; query = qq*16+g*4+r, d = dt*16+l15
    float mrun[4] = { -3e38f, -3e38f, -3e38f, -3e38f };
    float lrun[4] = { 0.0f, 0.0f, 0.0f, 0.0f };

    auto loadK = [&](bf16x8 (&kbX)[8], int c0) {
#pragma unroll
        for (int kt = 0; kt < 4; ++kt)
#pragma unroll
            for (int hh = 0; hh < 2; ++hh)
                kbX[kt * 2 + hh] =
                    *(const bf16x8*)&Kb[(size_t)(c0 + kt * 16 + l15) * DD + hh * 32 + g * 8];
    };
    auto loadV = [&](bf16x8 (&vbX)[8], int c0) {
#pragma unroll
        for (int dt = 0; dt < 4; ++dt)
#pragma unroll
            for (int kh = 0; kh < 2; ++kh)
                vbX[dt * 2 + kh] =
                    *(const bf16x8*)&Vb[(size_t)(dt * 16 + l15) * SS + c0 + kh * 32 + g * 8];
    };

    auto process = [&](const bf16x8 (&kbX)[8], const bf16x8 (&vbX)[8], int c0) {
#pragma unroll
        for (int qq = 0; qq < 4; ++qq) {
            // QK^T (swapped): s[kt][r] = score2(key c0+kt*16+g*4+r, query qw0+qq*16+l15)
            f32x4 s[4];
#pragma unroll
            for (int kt = 0; kt < 4; ++kt) {
                f32x4 a = {};
                a = __builtin_amdgcn_mfma_f32_16x16x32_bf16(kbX[kt * 2 + 0], qf[qq][0], a, 0, 0, 0);
                a = __builtin_amdgcn_mfma_f32_16x16x32_bf16(kbX[kt * 2 + 1], qf[qq][1], a, 0, 0, 0);
                s[kt] = a;
            }
            // tail clamp BEFORE the max (pad keys -> -3e38 -> P=0 exactly)
            if (c0 + 64 > L) {
#pragma unroll
                for (int kt = 0; kt < 4; ++kt) {
                    const int kid = c0 + kt * 16 + g * 4;
#pragma unroll
                    for (int r = 0; r < 4; ++r)
                        s[kt][r] = (kid + r < L) ? s[kt][r] : -3e38f;
                }
            }
            // chunk max (tree; per query l15)
            float pmk[4];
#pragma unroll
            for (int kt = 0; kt < 4; ++kt)
                pmk[kt] = fmaxf(fmaxf(s[kt][0], s[kt][1]), fmaxf(s[kt][2], s[kt][3]));
            float pm = fmaxf(fmaxf(pmk[0], pmk[1]), fmaxf(pmk[2], pmk[3]));
            pm = fmaxf(pm, __shfl_xor(pm, 16));
            pm = fmaxf(pm, __shfl_xor(pm, 32));

            // defer-max: rescale only when max grows past 8*log2e (wave-uniform)
            if (!__all(pm <= mrun[qq] + 11.5416f)) {
                float sc = exp2fast(mrun[qq] - pm);   // first chunk: exp2(-huge)=0
                mrun[qq] = pm;
                lrun[qq] *= sc;
                float f0 = __shfl(sc, g * 4 + 0);
                float f1 = __shfl(sc, g * 4 + 1);
                float f2 = __shfl(sc, g * 4 + 2);
                float f3 = __shfl(sc, g * 4 + 3);
#pragma unroll
                for (int dt = 0; dt < 4; ++dt) {
                    o[qq][dt][0] *= f0; o[qq][dt][1] *= f1;
                    o[qq][dt][2] *= f2; o[qq][dt][3] *= f3;
                }
            }

            // P~ = exp2(s - mrun) -> bf16 LDS (transpose to query-major), local sum
            float ls = 0.0f;
#pragma unroll
            for (int kt = 0; kt < 4; ++kt) {
                union { u16x4 v; u16 u[4]; } pv;
#pragma unroll
                for (int r = 0; r < 4; ++r) {
                    float e = exp2fast(s[kt][r] - mrun[qq]);
                    ls += e;
                    pv.u[r] = bfc(e);
                }
                *(u16x4*)&Pw[wave][qq & 1][l15][kt * 16 + g * 4] = pv.v;
            }
            ls += __shfl_xor(ls, 16);
            ls += __shfl_xor(ls, 32);
            lrun[qq] += ls;

            // PV: O[q][d] += P~ . V
#pragma unroll
            for (int kh = 0; kh < 2; ++kh) {
                bf16x8 pa = *(const bf16x8*)&Pw[wave][qq & 1][l15][kh * 32 + g * 8];
#pragma unroll
                for (int dt = 0; dt < 4; ++dt)
                    o[qq][dt] = __builtin_amdgcn_mfma_f32_16x16x32_bf16(pa, vbX[dt * 2 + kh], o[qq][dt], 0, 0, 0);
            }
        }
    };

    bf16x8 kbA[8], kbB[8];
    loadK(kbA, 0);
    for (int t = 0; t < npairs; ++t) {
        const int cA = t * 128;
        bf16x8 vbA[8];
        loadV(vbA, cA);
        loadK(kbB, cA + 64);
        process(kbA, vbA, cA);
        bf16x8 vbB[8];
        loadV(vbB, cA + 64);
        if (t + 1 < npairs) loadK(kbA, (t + 1) * 128);
        process(kbB, vbB, cA + 64);
    }

    // ---- epilogue: normalize per query, write ctx bf16 ----
#pragma unroll
    for (int qq = 0; qq < 4; ++qq) {
        float inv = 1.0f / lrun[qq];           // valid for query l15 (uniform over g)
        float i0 = __shfl(inv, g * 4 + 0);
        float i1 = __shfl(inv, g * 4 + 1);
        float i2 = __shfl(inv, g * 4 + 2);
        float i3 = __shfl(inv, g * 4 + 3);
#pragma unroll
        for (int dt = 0; dt < 4; ++dt) {
            const int col = h * DD + dt * 16 + l15;
            const int qr  = b * SS + qw0 + qq * 16 + g * 4;
            ctx[(size_t)(qr + 0) * HSZ + col] = bfc(o[qq][dt][0] * i0);
            ctx[(size_t)(qr + 1) * HSZ + col] = bfc(o[qq][dt][1] * i1);
            ctx[(size_t)(qr + 2) * HSZ + col] = bfc(o[qq][dt][2] * i2);
            ctx[(size_t)(qr + 3) * HSZ + col] = bfc(o[qq][dt][3] * i3);
        }
    }
}

// ---------------------------------------------------------------------------
extern "C" void kernel_launch(void* const* d_in, const int* in_sizes, int n_in,
                              void* d_out, int out_size, void* d_ws, size_t ws_size,
                              hipStream_t stream) {
    const float* v    = (const float*)d_in[0];
    const float* k    = (const float*)d_in[1];
    const float* q    = (const float*)d_in[2];
    const void*  mask = d_in[3];
    const float* Wq = (const float*)d_in[4];
    const float* bq = (const float*)d_in[5];
    const float* Wk = (const float*)d_in[6];
    const float* bk = (const float*)d_in[7];
    const float* Wv = (const float*)d_in[8];
    const float* bv = (const float*)d_in[9];
    const float* Wo = (const float*)d_in[10];
    const float* bo = (const float*)d_in[11];

    // d_out (32 MB f32, fully rewritten by the final proj_o) doubles as
    // scratch for the q/k bf16 staging buffers before proj_o runs.
    u16* qbf = (u16*)d_out;                         // 16 MB (dead after proj z=0)
    u16* kbf = qbf + (size_t)NTOK * HSZ;            // 16 MB (dead after proj z=1)

    char* ws = (char*)d_ws;
    int*   rmap = (int*)ws;                         // 32 KB
    int*   Larr = (int*)(ws + 32768);               // 32 B
    u16*   wqb  = (u16*)(ws + 65536);               // 2 MB each
    u16*   wkb  = wqb + (size_t)HSZ * HSZ;
    u16*   wvb  = wkb + (size_t)HSZ * HSZ;
    u16*   wob  = wvb + (size_t)HSZ * HSZ;
    u16*   vbf  = wob + (size_t)HSZ * HSZ;          // 16 MB (v bf16; ctx overlays)
    u16*   Qh   = vbf + (size_t)NTOK * HSZ;         // 16 MB each
    u16*   Kh   = Qh + (size_t)NTOK * HSZ;
    u16*   Vt   = Kh + (size_t)NTOK * HSZ;
    u16*   ctx  = vbf;                              // reuse (free after proj z=2)

    cvt_scan_kernel<<<NCVTB + BB, 256, 0, stream>>>(q, qbf, k, kbf, v, vbf,
                                                    Wq, wqb, Wk, wkb, Wv, wvb, Wo, wob,
                                                    mask, rmap, Larr);

    dim3 pgrid(NTOK / 128, HSZ / 128, 3);   // (64, 8, 3)
    proj_qkv_kernel<<<pgrid, 256, 0, stream>>>(qbf, wqb, bq, Qh,
                                               kbf, wkb, bk, Kh,
                                               vbf, wvb, bv, Vt,
                                               rmap, Larr);

    dim3 agrid(SS / 256, HH, BB);           // (4, 16, 8)
    attn_kernel<<<agrid, 256, 0, stream>>>(Qh, Kh, Vt, Larr, ctx);

    dim3 ogrid(NTOK / 128, HSZ / 128);      // (64, 8)
    proj_o_kernel<<<ogrid, 256, 0, stream>>>(ctx, wob, bo, rmap, Larr, (float*)d_out);
}

// Round 14
// 186.490 us; speedup vs baseline: 1.1865x; 1.0407x over previous
//
#include <hip/hip_runtime.h>
#include <hip/hip_bf16.h>

// Problem constants
#define HH   16
#define DD   64
#define HSZ  1024
#define BB   8
#define SS   1024
#define NTOK (BB*SS)   // 8192
#define LOG2E 1.4426950408889634f
#define NCVTB 2048     // cvt blocks in the fused cvt+scan launch

typedef __attribute__((ext_vector_type(8))) short bf16x8;
typedef __attribute__((ext_vector_type(4))) float f32x4;
typedef unsigned short u16;
typedef __attribute__((ext_vector_type(4))) unsigned short u16x4;

__device__ __forceinline__ u16 bfc(float x) {
    __hip_bfloat16 h = __float2bfloat16(x);   // RNE; pairs into v_cvt_pk_bf16_f32
    return *(u16*)&h;
}

// 2^x via v_exp_f32 (native exp2). __exp2f is not declared on this toolchain.
__device__ __forceinline__ float exp2fast(float x) {
    return __builtin_amdgcn_exp2f(x);
}

// async global->LDS, 16B per lane. LDS dest is WAVE-UNIFORM base + lane*16;
// global src is per-lane (so gather via rmap and XOR-swizzled source are free).
__device__ __forceinline__ void gload16(const u16* g, u16* l) {
    __builtin_amdgcn_global_load_lds(
        (const __attribute__((address_space(1))) void*)g,
        (__attribute__((address_space(3))) void*)l, 16, 0, 0);
}

// ---------------------------------------------------------------------------
// Mask scan body (one 256-thread block per batch): rmap[b][j] = original row
// of the j-th UNMASKED key (mask==0 kept; reference maps mask==True -> -1e9
// -> weight exactly 0 in f32). Pad entries [L,SS) -> row 0 (finite data; attn
// clamps key>=L). Larr[b] = #kept. Mask format detected on-device: int32 bool
// => bytes at idx%4!=0 all zero.
// ---------------------------------------------------------------------------
__device__ __forceinline__ void mask_scan_body(const void* mask,
                                               int* __restrict__ rmap,
                                               int* __restrict__ Larr, int b) {
    const int tid = threadIdx.x;
    const unsigned char* mball = (const unsigned char*)mask;

    __shared__ int fmt_s;
    __shared__ int wtot[4];
    __shared__ int Ls;
    if (tid == 0) fmt_s = 0;
    __syncthreads();
    int nz = 0;
    for (int i = tid; i < BB * SS; i += 256)
        if ((i & 3) && mball[i]) nz = 1;
    if (nz) fmt_s = 1;          // benign race: all writers store 1
    __syncthreads();
    const int fmt = fmt_s;      // 1 = byte format

    const int base = tid * 4;
    int v[4];
#pragma unroll
    for (int e = 0; e < 4; ++e) {
        int val = fmt ? (int)mball[(size_t)b * SS + base + e]
                      : ((const int*)mask)[(size_t)b * SS + base + e];
        v[e] = (val == 0) ? 1 : 0;   // keep iff unmasked
    }
    int ts = v[0] + v[1] + v[2] + v[3];

    const int lane = tid & 63, wv = tid >> 6;
    int incl = ts;
#pragma unroll
    for (int d = 1; d < 64; d <<= 1) {
        int t = __shfl_up(incl, d);
        if (lane >= d) incl += t;
    }
    if (lane == 63) wtot[wv] = incl;
    __syncthreads();
    int woff = 0;
    for (int w = 0; w < wv; ++w) woff += wtot[w];
    int run = woff + incl - ts;   // exclusive prefix for this thread's first elem
#pragma unroll
    for (int e = 0; e < 4; ++e) {
        if (v[e]) rmap[(size_t)b * SS + run] = base + e;
        run += v[e];
    }
    __syncthreads();
    if (tid == 0) {
        Ls = wtot[0] + wtot[1] + wtot[2] + wtot[3];
        Larr[b] = Ls;
    }
    __syncthreads();
    for (int j = Ls + tid; j < SS; j += 256) rmap[(size_t)b * SS + j] = 0;
}

// ---------------------------------------------------------------------------
// Fused convert + mask scan. Blocks [0,NCVTB): grid-stride f32->bf16 over 7
// regions (q,k,v inputs + 4 weights). Blocks [NCVTB,NCVTB+BB): mask scan for
// batch (blockIdx.x - NCVTB). The 2 µs scan hides under the BW-bound convert.
// ---------------------------------------------------------------------------
__global__ __launch_bounds__(256) void cvt_scan_kernel(
        const float* __restrict__ q,  u16* __restrict__ dq,
        const float* __restrict__ k,  u16* __restrict__ dk,
        const float* __restrict__ v,  u16* __restrict__ dv,
        const float* __restrict__ w0, u16* __restrict__ dw0,
        const float* __restrict__ w1, u16* __restrict__ dw1,
        const float* __restrict__ w2, u16* __restrict__ dw2,
        const float* __restrict__ w3, u16* __restrict__ dw3,
        const void* mask, int* __restrict__ rmap, int* __restrict__ Larr) {
    if (blockIdx.x >= NCVTB) {
        mask_scan_body(mask, rmap, Larr, blockIdx.x - NCVTB);
        return;
    }
    const int NX = NTOK * HSZ / 8;   // 1048576 units per input
    const int NW = HSZ * HSZ / 8;    // 131072 units per weight
    const int ntot = 3 * NX + 4 * NW;
    int i = blockIdx.x * blockDim.x + threadIdx.x;
    const int stride = NCVTB * 256;
    for (; i < ntot; i += stride) {
        const float* s; u16* d; int j = i;
        if      (j < NX)            { s = q;  d = dq;  }
        else if ((j -= NX) < NX)    { s = k;  d = dk;  }
        else if ((j -= NX) < NX)    { s = v;  d = dv;  }
        else if ((j -= NX) < NW)    { s = w0; d = dw0; }
        else if ((j -= NW) < NW)    { s = w1; d = dw1; }
        else if ((j -= NW) < NW)    { s = w2; d = dw2; }
        else    { j -= NW;            s = w3; d = dw3; }
        f32x4 a = *(const f32x4*)&s[(size_t)j * 8];
        f32x4 b = *(const f32x4*)&s[(size_t)j * 8 + 4];
        union { bf16x8 v8; u16 u[8]; } t;
#pragma unroll
        for (int e = 0; e < 4; ++e) { t.u[e] = bfc(a[e]); t.u[4 + e] = bfc(b[e]); }
        *(bf16x8*)&d[(size_t)j * 8] = t.v8;
    }
}

// ---------------------------------------------------------------------------
// Projection GEMM body: Y = X(bf16) @ W(bf16)^T + b.  BM=BN=128, BK=64,
// 4 waves (2x2), 4x4 frags/wave; both tiles staged via global_load_lds.
// BK=64 halves the vmcnt-drain+barrier count vs BK=32 (32 MFMA per drain).
// Row stride 128 B would be a 32-way bank conflict on ds_read_b128; fixed per
// rule #21: LDS dest stays LINEAR (gload_lds requirement), the global SOURCE
// column is pre-swizzled with slot^=(row&7), and the ds_read uses the same
// involution -> each g-group's 16 lanes span all 8 bank-groups (2-way, free).
// MODE 0: Q -> bf16 [B,H,S,D], scaled by (1/8)*log2e  (all 8192 rows)
// MODE 1: K -> bf16 [B,H,Scomp,D]  gather via rmap, compacted output
// MODE 2: V -> bf16 [B,H,D,Scomp]  gather + transpose
// MODE 3: ctx(bf16) @ Wo^T + bo -> f32 [B,S,HS] (d_out)
// ---------------------------------------------------------------------------
template<int MODE>
__device__ __forceinline__ void proj_body(const u16* __restrict__ X,
                                          const u16* __restrict__ W,
                                          const float* __restrict__ bias,
                                          const int* __restrict__ rmap,
                                          const int* __restrict__ Larr,
                                          void* __restrict__ Yv,
                                          u16* Xs, u16* Ws) {
    const int bm = blockIdx.x;
    const int bn = blockIdx.y;
    const int tid  = threadIdx.x;
    const int wave = tid >> 6;
    const int lane = tid & 63;
    const int l15  = lane & 15;
    const int g    = lane >> 4;
    const int wr   = wave >> 1;
    const int wc   = wave & 1;

    const int b_   = bm >> 3;          // batch (MODE 1/2)
    const int row0 = (bm & 7) * 128;   // compacted row base (MODE 1/2)
    if constexpr (MODE == 1 || MODE == 2) {
        const int L = Larr[b_];
        const int Lpad = ((L + 127) >> 7) << 7;
        if (row0 >= Lpad) return;      // block fully in dead pad region
    }

    f32x4 acc[4][4] = {};

    // staging geometry: tile = 128 rows x 64 cols bf16 = 1024 16B-slots;
    // thread covers 4 slots (issues). Linear slot -> (row = slot>>3, s = slot&7);
    // source column slot = s ^ (row&7)  (XOR involution, rule #21).
    int srow[4], scol[4], xr[4];
#pragma unroll
    for (int i = 0; i < 4; ++i) {
        const int slot = wave * 256 + i * 64 + lane;
        const int r = slot >> 3, s = slot & 7;
        srow[i] = r;
        scol[i] = (s ^ (r & 7)) * 8;   // swizzled source column (shorts)
        if constexpr (MODE == 1 || MODE == 2)
            xr[i] = (b_ << 10) + rmap[(size_t)b_ * SS + row0 + r];
        else
            xr[i] = bm * 128 + r;
    }

    for (int k0 = 0; k0 < HSZ; k0 += 64) {
#pragma unroll
        for (int i = 0; i < 4; ++i) {
            gload16(&X[(size_t)xr[i] * HSZ + k0 + scol[i]], &Xs[(wave * 4 + i) * 512]);
            gload16(&W[(size_t)(bn * 128 + srow[i]) * HSZ + k0 + scol[i]],
                    &Ws[(wave * 4 + i) * 512]);
        }
        __syncthreads();   // implicit vmcnt(0) drain completes gloads

#pragma unroll
        for (int kk = 0; kk < 2; ++kk) {
            // fragment column slot = kk*4+g, read through the same involution;
            // row&7 == l15&7 (wr*64, m*16 are 0 mod 8)
            const int cw = ((kk * 4 + g) ^ (l15 & 7)) * 8;
            bf16x8 a[4], bb[4];
#pragma unroll
            for (int m = 0; m < 4; ++m)
                a[m] = *(const bf16x8*)&Xs[(size_t)(wr * 64 + m * 16 + l15) * 64 + cw];
#pragma unroll
            for (int n = 0; n < 4; ++n)
                bb[n] = *(const bf16x8*)&Ws[(size_t)(wc * 64 + n * 16 + l15) * 64 + cw];
#pragma unroll
            for (int m = 0; m < 4; ++m)
#pragma unroll
                for (int n = 0; n < 4; ++n)
                    acc[m][n] = __builtin_amdgcn_mfma_f32_16x16x32_bf16(a[m], bb[n], acc[m][n], 0, 0, 0);
        }
        __syncthreads();
    }

    // ---- epilogue ----
#pragma unroll
    for (int m = 0; m < 4; ++m) {
#pragma unroll
        for (int n = 0; n < 4; ++n) {
            const int o = bn * 128 + wc * 64 + n * 16 + l15;
            const float bvv = bias[o];
            const int h_ = o >> 6, d = o & 63;
#pragma unroll
            for (int r = 0; r < 4; ++r) {
                const int lrow = wr * 64 + m * 16 + g * 4 + r;   // 0..127 in block
                float y = acc[m][n][r] + bvv;
                if constexpr (MODE == 0) {
                    const int nrow = bm * 128 + lrow;
                    int bb_ = nrow >> 10, s = nrow & 1023;
                    ((u16*)Yv)[(((size_t)bb_ * HH + h_) * SS + s) * DD + d] = bfc(y * (0.125f * LOG2E));
                } else if constexpr (MODE == 1) {
                    ((u16*)Yv)[(((size_t)b_ * HH + h_) * SS + row0 + lrow) * DD + d] = bfc(y);
                } else if constexpr (MODE == 2) {
                    ((u16*)Yv)[(((size_t)b_ * HH + h_) * DD + d) * SS + row0 + lrow] = bfc(y);
                } else {
                    const int nrow = bm * 128 + lrow;
                    ((float*)Yv)[(size_t)nrow * HSZ + o] = y;
                }
            }
        }
    }
}

// Fused Q/K/V projection: blockIdx.z selects the projection (packing fills
// CUs through proj<1>/<2>'s ~45% early-exit blocks, removes 2 launch gaps).
__global__ __launch_bounds__(256) void proj_qkv_kernel(
        const u16* __restrict__ qbf, const u16* __restrict__ wqb,
        const float* __restrict__ bq, u16* __restrict__ Qh,
        const u16* __restrict__ kbf, const u16* __restrict__ wkb,
        const float* __restrict__ bk, u16* __restrict__ Kh,
        const u16* __restrict__ vbf, const u16* __restrict__ wvb,
        const float* __restrict__ bv, u16* __restrict__ Vt,
        const int* __restrict__ rmap, const int* __restrict__ Larr) {
    __shared__ u16 Xs[128 * 64];   // 16 KB, linear (gload_lds dest)
    __shared__ u16 Ws[128 * 64];   // 16 KB
    if (blockIdx.z == 0)      proj_body<0>(qbf, wqb, bq, rmap, Larr, Qh, Xs, Ws);
    else if (blockIdx.z == 1) proj_body<1>(kbf, wkb, bk, rmap, Larr, Kh, Xs, Ws);
    else                      proj_body<2>(vbf, wvb, bv, rmap, Larr, Vt, Xs, Ws);
}

__global__ __launch_bounds__(256) void proj_o_kernel(
        const u16* __restrict__ X, const u16* __restrict__ W,
        const float* __restrict__ bias, const int* __restrict__ rmap,
        const int* __restrict__ Larr, float* __restrict__ out) {
    __shared__ u16 Xs[128 * 64];
    __shared__ u16 Ws[128 * 64];
    proj_body<3>(X, W, bias, rmap, Larr, out, Xs, Ws);
}

// ---------------------------------------------------------------------------
// Attention over COMPACTED keys (round-12 proven config, UNCHANGED: qq=4,
// 256 q/block, grid 512, __launch_bounds__(256,2), VGPR 128, 63.5 µs).
// Swapped QK^T keeps scores lane-local (query = l15); tail clamp BEFORE the
// max. Online softmax, defer-max, exp2. s_setprio tested r11: -10 µs, out.
// ---------------------------------------------------------------------------
__global__ __launch_bounds__(256, 2) void attn_kernel(const u16* __restrict__ Qh,
                                                      const u16* __restrict__ Kh,
                                                      const u16* __restrict__ Vt,
                                                      const int* __restrict__ Larr,
                                                      u16* __restrict__ ctx) {
    const int qt = blockIdx.x;   // 0..3
    const int h  = blockIdx.y;   // 0..15
    const int b  = blockIdx.z;   // 0..7
    const int bh = b * HH + h;

    const int tid  = threadIdx.x;
    const int wave = tid >> 6;
    const int lane = tid & 63;
    const int l15  = lane & 15;
    const int g    = lane >> 4;
    const int qw0  = qt * 256 + wave * 64;   // first query of this wave

    __shared__ u16 Pw[4][2][16][72];         // 18 KB; stride 72 -> 2-way banks (free)

    const u16* Qb = Qh + ((size_t)bh * SS + qw0) * DD;
    const u16* Kb = Kh + (size_t)bh * SS * DD;
    const u16* Vb = Vt + (size_t)bh * DD * SS;

    const int L = Larr[b];
    const int npairs = (L + 127) >> 7;

    // Q fragments: qf[qq][half] = Q[qw0+qq*16+l15][half*32 + g*8 ..+8]
    bf16x8 qf[4][2];
#pragma unroll
    for (int qq = 0; qq < 4; ++qq)
#pragma unroll
        for (int hh = 0; hh < 2; ++hh)
            qf[qq][hh] = *(const bf16x8*)&Qb[(size_t)(qq * 16 + l15) * DD + hh * 32 + g * 8];

    f32x4 o[4][4] = {};                      // [qq][dt]; query = qq*16+g*4+r, d = dt*16+l15
    float mrun[4] = { -3e38f, -3e38f, -3e38f, -3e38f };
    float lrun[4] = { 0.0f, 0.0f, 0.0f, 0.0f };

    auto loadK = [&](bf16x8 (&kbX)[8], int c0) {
#pragma unroll
        for (int kt = 0; kt < 4; ++kt)
#pragma unroll
            for (int hh = 0; hh < 2; ++hh)
                kbX[kt * 2 + hh] =
                    *(const bf16x8*)&Kb[(size_t)(c0 + kt * 16 + l15) * DD + hh * 32 + g * 8];
    };
    auto loadV = [&](bf16x8 (&vbX)[8], int c0) {
#pragma unroll
        for (int dt = 0; dt < 4; ++dt)
#pragma unroll
            for (int kh = 0; kh < 2; ++kh)
                vbX[dt * 2 + kh] =
                    *(const bf16x8*)&Vb[(size_t)(dt * 16 + l15) * SS + c0 + kh * 32 + g * 8];
    };

    auto process = [&](const bf16x8 (&kbX)[8], const bf16x8 (&vbX)[8], int c0) {
#pragma unroll
        for (int qq = 0; qq < 4; ++qq) {
            // QK^T (swapped): s[kt][r] = score2(key c0+kt*16+g*4+r, query qw0+qq*16+l15)
            f32x4 s[4];
#pragma unroll
            for (int kt = 0; kt < 4; ++kt) {
                f32x4 a = {};
                a = __builtin_amdgcn_mfma_f32_16x16x32_bf16(kbX[kt * 2 + 0], qf[qq][0], a, 0, 0, 0);
                a = __builtin_amdgcn_mfma_f32_16x16x32_bf16(kbX[kt * 2 + 1], qf[qq][1], a, 0, 0, 0);
                s[kt] = a;
            }
            // tail clamp BEFORE the max (pad keys -> -3e38 -> P=0 exactly)
            if (c0 + 64 > L) {
#pragma unroll
                for (int kt = 0; kt < 4; ++kt) {
                    const int kid = c0 + kt * 16 + g * 4;
#pragma unroll
                    for (int r = 0; r < 4; ++r)
                        s[kt][r] = (kid + r < L) ? s[kt][r] : -3e38f;
                }
            }
            // chunk max (tree; per query l15)
            float pmk[4];
#pragma unroll
            for (int kt = 0; kt < 4; ++kt)
                pmk[kt] = fmaxf(fmaxf(s[kt][0], s[kt][1]), fmaxf(s[kt][2], s[kt][3]));
            float pm = fmaxf(fmaxf(pmk[0], pmk[1]), fmaxf(pmk[2], pmk[3]));
            pm = fmaxf(pm, __shfl_xor(pm, 16));
            pm = fmaxf(pm, __shfl_xor(pm, 32));

            // defer-max: rescale only when max grows past 8*log2e (wave-uniform)
            if (!__all(pm <= mrun[qq] + 11.5416f)) {
                float sc = exp2fast(mrun[qq] - pm);   // first chunk: exp2(-huge)=0
                mrun[qq] = pm;
                lrun[qq] *= sc;
                float f0 = __shfl(sc, g * 4 + 0);
                float f1 = __shfl(sc, g * 4 + 1);
                float f2 = __shfl(sc, g * 4 + 2);
                float f3 = __shfl(sc, g * 4 + 3);
#pragma unroll
                for (int dt = 0; dt < 4; ++dt) {
                    o[qq][dt][0] *= f0; o[qq][dt][1] *= f1;
                    o[qq][dt][2] *= f2; o[qq][dt][3] *= f3;
                }
            }

            // P~ = exp2(s - mrun) -> bf16 LDS (transpose to query-major), local sum
            float ls = 0.0f;
#pragma unroll
            for (int kt = 0; kt < 4; ++kt) {
                union { u16x4 v; u16 u[4]; } pv;
#pragma unroll
                for (int r = 0; r < 4; ++r) {
                    float e = exp2fast(s[kt][r] - mrun[qq]);
                    ls += e;
                    pv.u[r] = bfc(e);
                }
                *(u16x4*)&Pw[wave][qq & 1][l15][kt * 16 + g * 4] = pv.v;
            }
            ls += __shfl_xor(ls, 16);
            ls += __shfl_xor(ls, 32);
            lrun[qq] += ls;

            // PV: O[q][d] += P~ . V
#pragma unroll
            for (int kh = 0; kh < 2; ++kh) {
                bf16x8 pa = *(const bf16x8*)&Pw[wave][qq & 1][l15][kh * 32 + g * 8];
#pragma unroll
                for (int dt = 0; dt < 4; ++dt)
                    o[qq][dt] = __builtin_amdgcn_mfma_f32_16x16x32_bf16(pa, vbX[dt * 2 + kh], o[qq][dt], 0, 0, 0);
            }
        }
    };

    bf16x8 kbA[8], kbB[8];
    loadK(kbA, 0);
    for (int t = 0; t < npairs; ++t) {
        const int cA = t * 128;
        bf16x8 vbA[8];
        loadV(vbA, cA);
        loadK(kbB, cA + 64);
        process(kbA, vbA, cA);
        bf16x8 vbB[8];
        loadV(vbB, cA + 64);
        if (t + 1 < npairs) loadK(kbA, (t + 1) * 128);
        process(kbB, vbB, cA + 64);
    }

    // ---- epilogue: normalize per query, write ctx bf16 ----
#pragma unroll
    for (int qq = 0; qq < 4; ++qq) {
        float inv = 1.0f / lrun[qq];           // valid for query l15 (uniform over g)
        float i0 = __shfl(inv, g * 4 + 0);
        float i1 = __shfl(inv, g * 4 + 1);
        float i2 = __shfl(inv, g * 4 + 2);
        float i3 = __shfl(inv, g * 4 + 3);
#pragma unroll
        for (int dt = 0; dt < 4; ++dt) {
            const int col = h * DD + dt * 16 + l15;
            const int qr  = b * SS + qw0 + qq * 16 + g * 4;
            ctx[(size_t)(qr + 0) * HSZ + col] = bfc(o[qq][dt][0] * i0);
            ctx[(size_t)(qr + 1) * HSZ + col] = bfc(o[qq][dt][1] * i1);
            ctx[(size_t)(qr + 2) * HSZ + col] = bfc(o[qq][dt][2] * i2);
            ctx[(size_t)(qr + 3) * HSZ + col] = bfc(o[qq][dt][3] * i3);
        }
    }
}

// ---------------------------------------------------------------------------
extern "C" void kernel_launch(void* const* d_in, const int* in_sizes, int n_in,
                              void* d_out, int out_size, void* d_ws, size_t ws_size,
                              hipStream_t stream) {
    const float* v    = (const float*)d_in[0];
    const float* k    = (const float*)d_in[1];
    const float* q    = (const float*)d_in[2];
    const void*  mask = d_in[3];
    const float* Wq = (const float*)d_in[4];
    const float* bq = (const float*)d_in[5];
    const float* Wk = (const float*)d_in[6];
    const float* bk = (const float*)d_in[7];
    const float* Wv = (const float*)d_in[8];
    const float* bv = (const float*)d_in[9];
    const float* Wo = (const float*)d_in[10];
    const float* bo = (const float*)d_in[11];

    // d_out (32 MB f32, fully rewritten by the final proj_o) doubles as
    // scratch for the q/k bf16 staging buffers before proj_o runs.
    u16* qbf = (u16*)d_out;                         // 16 MB (dead after proj z=0)
    u16* kbf = qbf + (size_t)NTOK * HSZ;            // 16 MB (dead after proj z=1)

    char* ws = (char*)d_ws;
    int*   rmap = (int*)ws;                         // 32 KB
    int*   Larr = (int*)(ws + 32768);               // 32 B
    u16*   wqb  = (u16*)(ws + 65536);               // 2 MB each
    u16*   wkb  = wqb + (size_t)HSZ * HSZ;
    u16*   wvb  = wkb + (size_t)HSZ * HSZ;
    u16*   wob  = wvb + (size_t)HSZ * HSZ;
    u16*   vbf  = wob + (size_t)HSZ * HSZ;          // 16 MB (v bf16; ctx overlays)
    u16*   Qh   = vbf + (size_t)NTOK * HSZ;         // 16 MB each
    u16*   Kh   = Qh + (size_t)NTOK * HSZ;
    u16*   Vt   = Kh + (size_t)NTOK * HSZ;
    u16*   ctx  = vbf;                              // reuse (free after proj z=2)

    cvt_scan_kernel<<<NCVTB + BB, 256, 0, stream>>>(q, qbf, k, kbf, v, vbf,
                                                    Wq, wqb, Wk, wkb, Wv, wvb, Wo, wob,
                                                    mask, rmap, Larr);

    dim3 pgrid(NTOK / 128, HSZ / 128, 3);   // (64, 8, 3)
    proj_qkv_kernel<<<pgrid, 256, 0, stream>>>(qbf, wqb, bq, Qh,
                                               kbf, wkb, bk, Kh,
                                               vbf, wvb, bv, Vt,
                                               rmap, Larr);

    dim3 agrid(SS / 256, HH, BB);           // (4, 16, 8)
    attn_kernel<<<agrid, 256, 0, stream>>>(Qh, Kh, Vt, Larr, ctx);

    dim3 ogrid(NTOK / 128, HSZ / 128);      // (64, 8)
    proj_o_kernel<<<ogrid, 256, 0, stream>>>(ctx, wob, bo, rmap, Larr, (float*)d_out);
}

// Round 15
// 166.003 us; speedup vs baseline: 1.3330x; 1.1234x over previous
//
#include <hip/hip_runtime.h>
#include <hip/hip_bf16.h>

// Problem constants
#define HH   16
#define DD   64
#define HSZ  1024
#define BB   8
#define SS   1024
#define NTOK (BB*SS)   // 8192
#define LOG2E 1.4426950408889634f
#define NCVTB 2048     // cvt blocks in the fused cvt+scan launch

typedef __attribute__((ext_vector_type(8))) short bf16x8;
typedef __attribute__((ext_vector_type(4))) float f32x4;
typedef unsigned short u16;
typedef __attribute__((ext_vector_type(4))) unsigned short u16x4;

__device__ __forceinline__ u16 bfc(float x) {
    __hip_bfloat16 h = __float2bfloat16(x);   // RNE; pairs into v_cvt_pk_bf16_f32
    return *(u16*)&h;
}

// 2^x via v_exp_f32 (native exp2). __exp2f is not declared on this toolchain.
__device__ __forceinline__ float exp2fast(float x) {
    return __builtin_amdgcn_exp2f(x);
}

// async global->LDS, 16B per lane. LDS dest is WAVE-UNIFORM base + lane*16;
// global src is per-lane (so gather via rmap and XOR-swizzled source are free).
__device__ __forceinline__ void gload16(const u16* g, u16* l) {
    __builtin_amdgcn_global_load_lds(
        (const __attribute__((address_space(1))) void*)g,
        (__attribute__((address_space(3))) void*)l, 16, 0, 0);
}

// ---------------------------------------------------------------------------
// Mask scan body (one 256-thread block per batch): rmap[b][j] = original row
// of the j-th UNMASKED key (mask==0 kept; reference maps mask==True -> -1e9
// -> weight exactly 0 in f32). Pad entries [L,SS) -> row 0 (finite data; attn
// clamps key>=L). Larr[b] = #kept. Mask format detected on-device: int32 bool
// => bytes at idx%4!=0 all zero.
// ---------------------------------------------------------------------------
__device__ __forceinline__ void mask_scan_body(const void* mask,
                                               int* __restrict__ rmap,
                                               int* __restrict__ Larr, int b) {
    const int tid = threadIdx.x;
    const unsigned char* mball = (const unsigned char*)mask;

    __shared__ int fmt_s;
    __shared__ int wtot[4];
    __shared__ int Ls;
    if (tid == 0) fmt_s = 0;
    __syncthreads();
    int nz = 0;
    for (int i = tid; i < BB * SS; i += 256)
        if ((i & 3) && mball[i]) nz = 1;
    if (nz) fmt_s = 1;          // benign race: all writers store 1
    __syncthreads();
    const int fmt = fmt_s;      // 1 = byte format

    const int base = tid * 4;
    int v[4];
#pragma unroll
    for (int e = 0; e < 4; ++e) {
        int val = fmt ? (int)mball[(size_t)b * SS + base + e]
                      : ((const int*)mask)[(size_t)b * SS + base + e];
        v[e] = (val == 0) ? 1 : 0;   // keep iff unmasked
    }
    int ts = v[0] + v[1] + v[2] + v[3];

    const int lane = tid & 63, wv = tid >> 6;
    int incl = ts;
#pragma unroll
    for (int d = 1; d < 64; d <<= 1) {
        int t = __shfl_up(incl, d);
        if (lane >= d) incl += t;
    }
    if (lane == 63) wtot[wv] = incl;
    __syncthreads();
    int woff = 0;
    for (int w = 0; w < wv; ++w) woff += wtot[w];
    int run = woff + incl - ts;   // exclusive prefix for this thread's first elem
#pragma unroll
    for (int e = 0; e < 4; ++e) {
        if (v[e]) rmap[(size_t)b * SS + run] = base + e;
        run += v[e];
    }
    __syncthreads();
    if (tid == 0) {
        Ls = wtot[0] + wtot[1] + wtot[2] + wtot[3];
        Larr[b] = Ls;
    }
    __syncthreads();
    for (int j = Ls + tid; j < SS; j += 256) rmap[(size_t)b * SS + j] = 0;
}

// ---------------------------------------------------------------------------
// Fused convert + mask scan. Blocks [0,NCVTB): grid-stride f32->bf16 over 7
// regions (q,k,v inputs + 4 weights). Blocks [NCVTB,NCVTB+BB): mask scan for
// batch (blockIdx.x - NCVTB). The 2 µs scan hides under the BW-bound convert.
// ---------------------------------------------------------------------------
__global__ __launch_bounds__(256) void cvt_scan_kernel(
        const float* __restrict__ q,  u16* __restrict__ dq,
        const float* __restrict__ k,  u16* __restrict__ dk,
        const float* __restrict__ v,  u16* __restrict__ dv,
        const float* __restrict__ w0, u16* __restrict__ dw0,
        const float* __restrict__ w1, u16* __restrict__ dw1,
        const float* __restrict__ w2, u16* __restrict__ dw2,
        const float* __restrict__ w3, u16* __restrict__ dw3,
        const void* mask, int* __restrict__ rmap, int* __restrict__ Larr) {
    if (blockIdx.x >= NCVTB) {
        mask_scan_body(mask, rmap, Larr, blockIdx.x - NCVTB);
        return;
    }
    const int NX = NTOK * HSZ / 8;   // 1048576 units per input
    const int NW = HSZ * HSZ / 8;    // 131072 units per weight
    const int ntot = 3 * NX + 4 * NW;
    int i = blockIdx.x * blockDim.x + threadIdx.x;
    const int stride = NCVTB * 256;
    for (; i < ntot; i += stride) {
        const float* s; u16* d; int j = i;
        if      (j < NX)            { s = q;  d = dq;  }
        else if ((j -= NX) < NX)    { s = k;  d = dk;  }
        else if ((j -= NX) < NX)    { s = v;  d = dv;  }
        else if ((j -= NX) < NW)    { s = w0; d = dw0; }
        else if ((j -= NW) < NW)    { s = w1; d = dw1; }
        else if ((j -= NW) < NW)    { s = w2; d = dw2; }
        else    { j -= NW;            s = w3; d = dw3; }
        f32x4 a = *(const f32x4*)&s[(size_t)j * 8];
        f32x4 b = *(const f32x4*)&s[(size_t)j * 8 + 4];
        union { bf16x8 v8; u16 u[8]; } t;
#pragma unroll
        for (int e = 0; e < 4; ++e) { t.u[e] = bfc(a[e]); t.u[4 + e] = bfc(b[e]); }
        *(bf16x8*)&d[(size_t)j * 8] = t.v8;
    }
}

// ---------------------------------------------------------------------------
// Projection GEMM body: Y = X(bf16) @ W(bf16)^T + b.  BM=BN=128, BK=64,
// 4 waves (2x2), 4x4 frags/wave; both tiles staged via global_load_lds.
// BK=64 halves the vmcnt-drain+barrier count vs BK=32 (32 MFMA per drain).
// Rule-#21 XOR swizzle (slot^=(row&7)) on source + read: measured 0 bank
// conflicts (round 14).
// MODE 0: Q -> bf16 [B,H,S,D], scaled by (1/8)*log2e  (all 8192 rows)
// MODE 1: K -> bf16 [B,H,Scomp,D]  gather via rmap, compacted output
// MODE 2: V -> bf16 [B,H,D,Scomp]  gather + transpose
// MODE 3: ctx(bf16) @ Wo^T + bo -> f32 [B,S,HS] (d_out)
// ---------------------------------------------------------------------------
template<int MODE>
__device__ __forceinline__ void proj_body(const u16* __restrict__ X,
                                          const u16* __restrict__ W,
                                          const float* __restrict__ bias,
                                          const int* __restrict__ rmap,
                                          const int* __restrict__ Larr,
                                          void* __restrict__ Yv,
                                          u16* Xs, u16* Ws) {
    const int bm = blockIdx.x;
    const int bn = blockIdx.y;
    const int tid  = threadIdx.x;
    const int wave = tid >> 6;
    const int lane = tid & 63;
    const int l15  = lane & 15;
    const int g    = lane >> 4;
    const int wr   = wave >> 1;
    const int wc   = wave & 1;

    const int b_   = bm >> 3;          // batch (MODE 1/2)
    const int row0 = (bm & 7) * 128;   // compacted row base (MODE 1/2)
    if constexpr (MODE == 1 || MODE == 2) {
        const int L = Larr[b_];
        const int Lpad = ((L + 127) >> 7) << 7;
        if (row0 >= Lpad) return;      // block fully in dead pad region
    }

    f32x4 acc[4][4] = {};

    // staging geometry: tile = 128 rows x 64 cols bf16 = 1024 16B-slots;
    // thread covers 4 slots. slot -> (row = slot>>3, s = slot&7);
    // source column slot = s ^ (row&7)  (XOR involution, rule #21).
    int srow[4], scol[4], xr[4];
#pragma unroll
    for (int i = 0; i < 4; ++i) {
        const int slot = wave * 256 + i * 64 + lane;
        const int r = slot >> 3, s = slot & 7;
        srow[i] = r;
        scol[i] = (s ^ (r & 7)) * 8;   // swizzled source column (shorts)
        if constexpr (MODE == 1 || MODE == 2)
            xr[i] = (b_ << 10) + rmap[(size_t)b_ * SS + row0 + r];
        else
            xr[i] = bm * 128 + r;
    }

    for (int k0 = 0; k0 < HSZ; k0 += 64) {
#pragma unroll
        for (int i = 0; i < 4; ++i) {
            gload16(&X[(size_t)xr[i] * HSZ + k0 + scol[i]], &Xs[(wave * 4 + i) * 512]);
            gload16(&W[(size_t)(bn * 128 + srow[i]) * HSZ + k0 + scol[i]],
                    &Ws[(wave * 4 + i) * 512]);
        }
        __syncthreads();   // implicit vmcnt(0) drain completes gloads

#pragma unroll
        for (int kk = 0; kk < 2; ++kk) {
            const int cw = ((kk * 4 + g) ^ (l15 & 7)) * 8;
            bf16x8 a[4], bb[4];
#pragma unroll
            for (int m = 0; m < 4; ++m)
                a[m] = *(const bf16x8*)&Xs[(size_t)(wr * 64 + m * 16 + l15) * 64 + cw];
#pragma unroll
            for (int n = 0; n < 4; ++n)
                bb[n] = *(const bf16x8*)&Ws[(size_t)(wc * 64 + n * 16 + l15) * 64 + cw];
#pragma unroll
            for (int m = 0; m < 4; ++m)
#pragma unroll
                for (int n = 0; n < 4; ++n)
                    acc[m][n] = __builtin_amdgcn_mfma_f32_16x16x32_bf16(a[m], bb[n], acc[m][n], 0, 0, 0);
        }
        __syncthreads();
    }

    // ---- epilogue ----
#pragma unroll
    for (int m = 0; m < 4; ++m) {
#pragma unroll
        for (int n = 0; n < 4; ++n) {
            const int o = bn * 128 + wc * 64 + n * 16 + l15;
            const float bvv = bias[o];
            const int h_ = o >> 6, d = o & 63;
#pragma unroll
            for (int r = 0; r < 4; ++r) {
                const int lrow = wr * 64 + m * 16 + g * 4 + r;   // 0..127 in block
                float y = acc[m][n][r] + bvv;
                if constexpr (MODE == 0) {
                    const int nrow = bm * 128 + lrow;
                    int bb_ = nrow >> 10, s = nrow & 1023;
                    ((u16*)Yv)[(((size_t)bb_ * HH + h_) * SS + s) * DD + d] = bfc(y * (0.125f * LOG2E));
                } else if constexpr (MODE == 1) {
                    ((u16*)Yv)[(((size_t)b_ * HH + h_) * SS + row0 + lrow) * DD + d] = bfc(y);
                } else if constexpr (MODE == 2) {
                    ((u16*)Yv)[(((size_t)b_ * HH + h_) * DD + d) * SS + row0 + lrow] = bfc(y);
                } else {
                    const int nrow = bm * 128 + lrow;
                    ((float*)Yv)[(size_t)nrow * HSZ + o] = y;
                }
            }
        }
    }
}

// Fused Q/K/V projection: blockIdx.z selects the projection (packing fills
// CUs through proj<1>/<2>'s ~45% early-exit blocks, removes 2 launch gaps).
__global__ __launch_bounds__(256) void proj_qkv_kernel(
        const u16* __restrict__ qbf, const u16* __restrict__ wqb,
        const float* __restrict__ bq, u16* __restrict__ Qh,
        const u16* __restrict__ kbf, const u16* __restrict__ wkb,
        const float* __restrict__ bk, u16* __restrict__ Kh,
        const u16* __restrict__ vbf, const u16* __restrict__ wvb,
        const float* __restrict__ bv, u16* __restrict__ Vt,
        const int* __restrict__ rmap, const int* __restrict__ Larr) {
    __shared__ u16 Xs[128 * 64];   // 16 KB, linear (gload_lds dest)
    __shared__ u16 Ws[128 * 64];   // 16 KB
    if (blockIdx.z == 0)      proj_body<0>(qbf, wqb, bq, rmap, Larr, Qh, Xs, Ws);
    else if (blockIdx.z == 1) proj_body<1>(kbf, wkb, bk, rmap, Larr, Kh, Xs, Ws);
    else                      proj_body<2>(vbf, wvb, bv, rmap, Larr, Vt, Xs, Ws);
}

__global__ __launch_bounds__(256) void proj_o_kernel(
        const u16* __restrict__ X, const u16* __restrict__ W,
        const float* __restrict__ bias, const int* __restrict__ rmap,
        const int* __restrict__ Larr, float* __restrict__ out) {
    __shared__ u16 Xs[128 * 64];
    __shared__ u16 Ws[128 * 64];
    proj_body<3>(X, W, bias, rmap, Larr, out, Xs, Ws);
}

// ---------------------------------------------------------------------------
// Attention over COMPACTED keys. Block = (256 queries, one (b,h)); 4 waves x
// 64 queries (qq=4). NEW (r15): K/V chunks staged in LDS ONCE per block via
// gload16 (previously each wave redundantly loaded the same chunk -> 4x L2
// traffic), double-buffered with prefetch: issue chunk c+1's 4 gloads, compute
// chunk c (64 MFMA/wave), one __syncthreads per chunk (drains prefetch +
// guards buffer reuse). LDS frag reads use round-14's PROVEN XOR involution
// (slot^=(row&7), measured 0 conflicts). K/V frags held in regs per chunk
// (each reused across 4 qq). Swapped QK^T, online softmax, defer-max, exp2,
// tail clamp BEFORE max. s_setprio tested r11: -10 µs, out.
// ---------------------------------------------------------------------------
__global__ __launch_bounds__(256, 2) void attn_kernel(const u16* __restrict__ Qh,
                                                      const u16* __restrict__ Kh,
                                                      const u16* __restrict__ Vt,
                                                      const int* __restrict__ Larr,
                                                      u16* __restrict__ ctx) {
    const int qt = blockIdx.x;   // 0..3
    const int h  = blockIdx.y;   // 0..15
    const int b  = blockIdx.z;   // 0..7
    const int bh = b * HH + h;

    const int tid  = threadIdx.x;
    const int wave = tid >> 6;
    const int lane = tid & 63;
    const int l15  = lane & 15;
    const int g    = lane >> 4;
    const int qw0  = qt * 256 + wave * 64;   // first query of this wave

    __shared__ u16 Ks[2][64 * 64];           // 8 KB x2 (dbuf), XOR-swizzled rows
    __shared__ u16 Vs[2][64 * 64];           // 8 KB x2
    __shared__ u16 Pw[4][2][16][72];         // 18 KB; stride 72 -> 2-way (free)

    const u16* Qb = Qh + ((size_t)bh * SS + qw0) * DD;
    const u16* Kb = Kh + (size_t)bh * SS * DD;
    const u16* Vb = Vt + (size_t)bh * DD * SS;

    const int L = Larr[b];
    const int nchunks = (L + 63) >> 6;   // 64-key chunks; K/V rows < ceil128(L) valid

    // Q fragments: qf[qq][half] = Q[qw0+qq*16+l15][half*32 + g*8 ..+8]
    bf16x8 qf[4][2];
#pragma unroll
    for (int qq = 0; qq < 4; ++qq)
#pragma unroll
        for (int hh = 0; hh < 2; ++hh)
            qf[qq][hh] = *(const bf16x8*)&Qb[(size_t)(qq * 16 + l15) * DD + hh * 32 + g * 8];

    f32x4 o[4][4] = {};                      // [qq][dt]; query = qq*16+g*4+r, d = dt*16+l15
    float mrun[4] = { -3e38f, -3e38f, -3e38f, -3e38f };
    float lrun[4] = { 0.0f, 0.0f, 0.0f, 0.0f };

    // stage one 64x64 chunk of K and V into LDS parity p. 512 slots each;
    // thread covers slots tid and tid+256. LDS dest linear (wave-uniform base
    // + lane*16); SOURCE column pre-swizzled with the rule-#21 involution.
    auto stage = [&](u16* Kp, u16* Vp, int c0) {
#pragma unroll
        for (int i = 0; i < 2; ++i) {
            const int slot = i * 256 + tid;             // 0..511
            const int r  = slot >> 3;                   // tile row 0..63
            const int cs = ((slot & 7) ^ (r & 7)) * 8;  // swizzled src col (shorts)
            u16* dstK = Kp + (size_t)(i * 256 + wave * 64) * 8;
            u16* dstV = Vp + (size_t)(i * 256 + wave * 64) * 8;
            gload16(&Kb[(size_t)(c0 + r) * DD + cs], dstK);   // K rows = keys
            gload16(&Vb[(size_t)r * SS + c0 + cs],   dstV);   // V rows = d
        }
    };
    // frag reads through the same involution (row&7 == l15&7; kt/dt*16 = 0 mod 8)
    auto loadKfrag = [&](const u16* Kp, bf16x8 (&kf)[8]) {
#pragma unroll
        for (int kt = 0; kt < 4; ++kt)
#pragma unroll
            for (int hh = 0; hh < 2; ++hh) {
                const int cw = ((hh * 4 + g) ^ (l15 & 7)) * 8;
                kf[kt * 2 + hh] = *(const bf16x8*)&Kp[(size_t)(kt * 16 + l15) * 64 + cw];
            }
    };
    auto loadVfrag = [&](const u16* Vp, bf16x8 (&vf)[8]) {
#pragma unroll
        for (int dt = 0; dt < 4; ++dt)
#pragma unroll
            for (int kh = 0; kh < 2; ++kh) {
                const int cw = ((kh * 4 + g) ^ (l15 & 7)) * 8;
                vf[dt * 2 + kh] = *(const bf16x8*)&Vp[(size_t)(dt * 16 + l15) * 64 + cw];
            }
    };

    auto process = [&](const bf16x8 (&kf)[8], const bf16x8 (&vf)[8], int c0) {
#pragma unroll
        for (int qq = 0; qq < 4; ++qq) {
            // QK^T (swapped): s[kt][r] = score2(key c0+kt*16+g*4+r, query qw0+qq*16+l15)
            f32x4 s[4];
#pragma unroll
            for (int kt = 0; kt < 4; ++kt) {
                f32x4 a = {};
                a = __builtin_amdgcn_mfma_f32_16x16x32_bf16(kf[kt * 2 + 0], qf[qq][0], a, 0, 0, 0);
                a = __builtin_amdgcn_mfma_f32_16x16x32_bf16(kf[kt * 2 + 1], qf[qq][1], a, 0, 0, 0);
                s[kt] = a;
            }
            // tail clamp BEFORE the max (pad keys -> -3e38 -> P=0 exactly)
            if (c0 + 64 > L) {
#pragma unroll
                for (int kt = 0; kt < 4; ++kt) {
                    const int kid = c0 + kt * 16 + g * 4;
#pragma unroll
                    for (int r = 0; r < 4; ++r)
                        s[kt][r] = (kid + r < L) ? s[kt][r] : -3e38f;
                }
            }
            // chunk max (tree; per query l15)
            float pmk[4];
#pragma unroll
            for (int kt = 0; kt < 4; ++kt)
                pmk[kt] = fmaxf(fmaxf(s[kt][0], s[kt][1]), fmaxf(s[kt][2], s[kt][3]));
            float pm = fmaxf(fmaxf(pmk[0], pmk[1]), fmaxf(pmk[2], pmk[3]));
            pm = fmaxf(pm, __shfl_xor(pm, 16));
            pm = fmaxf(pm, __shfl_xor(pm, 32));

            // defer-max: rescale only when max grows past 8*log2e (wave-uniform)
            if (!__all(pm <= mrun[qq] + 11.5416f)) {
                float sc = exp2fast(mrun[qq] - pm);   // first chunk: exp2(-huge)=0
                mrun[qq] = pm;
                lrun[qq] *= sc;
                float f0 = __shfl(sc, g * 4 + 0);
                float f1 = __shfl(sc, g * 4 + 1);
                float f2 = __shfl(sc, g * 4 + 2);
                float f3 = __shfl(sc, g * 4 + 3);
#pragma unroll
                for (int dt = 0; dt < 4; ++dt) {
                    o[qq][dt][0] *= f0; o[qq][dt][1] *= f1;
                    o[qq][dt][2] *= f2; o[qq][dt][3] *= f3;
                }
            }

            // P~ = exp2(s - mrun) -> bf16 LDS (transpose to query-major), local sum
            float ls = 0.0f;
#pragma unroll
            for (int kt = 0; kt < 4; ++kt) {
                union { u16x4 v; u16 u[4]; } pv;
#pragma unroll
                for (int r = 0; r < 4; ++r) {
                    float e = exp2fast(s[kt][r] - mrun[qq]);
                    ls += e;
                    pv.u[r] = bfc(e);
                }
                *(u16x4*)&Pw[wave][qq & 1][l15][kt * 16 + g * 4] = pv.v;
            }
            ls += __shfl_xor(ls, 16);
            ls += __shfl_xor(ls, 32);
            lrun[qq] += ls;

            // PV: O[q][d] += P~ . V
#pragma unroll
            for (int kh = 0; kh < 2; ++kh) {
                bf16x8 pa = *(const bf16x8*)&Pw[wave][qq & 1][l15][kh * 32 + g * 8];
#pragma unroll
                for (int dt = 0; dt < 4; ++dt)
                    o[qq][dt] = __builtin_amdgcn_mfma_f32_16x16x32_bf16(pa, vf[dt * 2 + kh], o[qq][dt], 0, 0, 0);
            }
        }
    };

    // main loop: prefetch c+1 while computing c; one barrier per chunk.
    stage(&Ks[0][0], &Vs[0][0], 0);
    __syncthreads();
    for (int c = 0; c < nchunks; ++c) {
        const int p = c & 1;
        if (c + 1 < nchunks) stage(&Ks[p ^ 1][0], &Vs[p ^ 1][0], (c + 1) * 64);
        bf16x8 kf[8], vf[8];
        loadKfrag(&Ks[p][0], kf);
        loadVfrag(&Vs[p][0], vf);
        process(kf, vf, c * 64);
        __syncthreads();   // drains prefetch gloads; all waves done with buf p
    }

    // ---- epilogue: normalize per query, write ctx bf16 ----
#pragma unroll
    for (int qq = 0; qq < 4; ++qq) {
        float inv = 1.0f / lrun[qq];           // valid for query l15 (uniform over g)
        float i0 = __shfl(inv, g * 4 + 0);
        float i1 = __shfl(inv, g * 4 + 1);
        float i2 = __shfl(inv, g * 4 + 2);
        float i3 = __shfl(inv, g * 4 + 3);
#pragma unroll
        for (int dt = 0; dt < 4; ++dt) {
            const int col = h * DD + dt * 16 + l15;
            const int qr  = b * SS + qw0 + qq * 16 + g * 4;
            ctx[(size_t)(qr + 0) * HSZ + col] = bfc(o[qq][dt][0] * i0);
            ctx[(size_t)(qr + 1) * HSZ + col] = bfc(o[qq][dt][1] * i1);
            ctx[(size_t)(qr + 2) * HSZ + col] = bfc(o[qq][dt][2] * i2);
            ctx[(size_t)(qr + 3) * HSZ + col] = bfc(o[qq][dt][3] * i3);
        }
    }
}

// ---------------------------------------------------------------------------
extern "C" void kernel_launch(void* const* d_in, const int* in_sizes, int n_in,
                              void* d_out, int out_size, void* d_ws, size_t ws_size,
                              hipStream_t stream) {
    const float* v    = (const float*)d_in[0];
    const float* k    = (const float*)d_in[1];
    const float* q    = (const float*)d_in[2];
    const void*  mask = d_in[3];
    const float* Wq = (const float*)d_in[4];
    const float* bq = (const float*)d_in[5];
    const float* Wk = (const float*)d_in[6];
    const float* bk = (const float*)d_in[7];
    const float* Wv = (const float*)d_in[8];
    const float* bv = (const float*)d_in[9];
    const float* Wo = (const float*)d_in[10];
    const float* bo = (const float*)d_in[11];

    // d_out (32 MB f32, fully rewritten by the final proj_o) doubles as
    // scratch for the q/k bf16 staging buffers before proj_o runs.
    u16* qbf = (u16*)d_out;                         // 16 MB (dead after proj z=0)
    u16* kbf = qbf + (size_t)NTOK * HSZ;            // 16 MB (dead after proj z=1)

    char* ws = (char*)d_ws;
    int*   rmap = (int*)ws;                         // 32 KB
    int*   Larr = (int*)(ws + 32768);               // 32 B
    u16*   wqb  = (u16*)(ws + 65536);               // 2 MB each
    u16*   wkb  = wqb + (size_t)HSZ * HSZ;
    u16*   wvb  = wkb + (size_t)HSZ * HSZ;
    u16*   wob  = wvb + (size_t)HSZ * HSZ;
    u16*   vbf  = wob + (size_t)HSZ * HSZ;          // 16 MB (v bf16; ctx overlays)
    u16*   Qh   = vbf + (size_t)NTOK * HSZ;         // 16 MB each
    u16*   Kh   = Qh + (size_t)NTOK * HSZ;
    u16*   Vt   = Kh + (size_t)NTOK * HSZ;
    u16*   ctx  = vbf;                              // reuse (free after proj z=2)

    cvt_scan_kernel<<<NCVTB + BB, 256, 0, stream>>>(q, qbf, k, kbf, v, vbf,
                                                    Wq, wqb, Wk, wkb, Wv, wvb, Wo, wob,
                                                    mask, rmap, Larr);

    dim3 pgrid(NTOK / 128, HSZ / 128, 3);   // (64, 8, 3)
    proj_qkv_kernel<<<pgrid, 256, 0, stream>>>(qbf, wqb, bq, Qh,
                                               kbf, wkb, bk, Kh,
                                               vbf, wvb, bv, Vt,
                                               rmap, Larr);

    dim3 agrid(SS / 256, HH, BB);           // (4, 16, 8)
    attn_kernel<<<agrid, 256, 0, stream>>>(Qh, Kh, Vt, Larr, ctx);

    dim3 ogrid(NTOK / 128, HSZ / 128);      // (64, 8)
    proj_o_kernel<<<ogrid, 256, 0, stream>>>(ctx, wob, bo, rmap, Larr, (float*)d_out);
}

// Round 16
// 157.474 us; speedup vs baseline: 1.4052x; 1.0542x over previous
//
#include <hip/hip_runtime.h>
#include <hip/hip_bf16.h>

// Problem constants
#define HH   16
#define DD   64
#define HSZ  1024
#define BB   8
#define SS   1024
#define NTOK (BB*SS)   // 8192
#define LOG2E 1.4426950408889634f
#define NCVTB 2048     // cvt blocks in the fused cvt+scan launch

typedef __attribute__((ext_vector_type(8))) short bf16x8;
typedef __attribute__((ext_vector_type(4))) float f32x4;
typedef unsigned short u16;
typedef __attribute__((ext_vector_type(4))) unsigned short u16x4;

__device__ __forceinline__ u16 bfc(float x) {
    __hip_bfloat16 h = __float2bfloat16(x);   // RNE; pairs into v_cvt_pk_bf16_f32
    return *(u16*)&h;
}

// 2^x via v_exp_f32 (native exp2). __exp2f is not declared on this toolchain.
__device__ __forceinline__ float exp2fast(float x) {
    return __builtin_amdgcn_exp2f(x);
}

// async global->LDS, 16B per lane. LDS dest is WAVE-UNIFORM base + lane*16;
// global src is per-lane (so gather via rmap and XOR-swizzled source are free).
__device__ __forceinline__ void gload16(const u16* g, u16* l) {
    __builtin_amdgcn_global_load_lds(
        (const __attribute__((address_space(1))) void*)g,
        (__attribute__((address_space(3))) void*)l, 16, 0, 0);
}

// ---------------------------------------------------------------------------
// Mask scan body (one 256-thread block per batch): rmap[b][j] = original row
// of the j-th UNMASKED key (mask==0 kept; reference maps mask==True -> -1e9
// -> weight exactly 0 in f32). Pad entries [L,SS) -> row 0 (finite data; attn
// clamps key>=L). Larr[b] = #kept. Mask format detected on-device: int32 bool
// => bytes at idx%4!=0 all zero.
// ---------------------------------------------------------------------------
__device__ __forceinline__ void mask_scan_body(const void* mask,
                                               int* __restrict__ rmap,
                                               int* __restrict__ Larr, int b) {
    const int tid = threadIdx.x;
    const unsigned char* mball = (const unsigned char*)mask;

    __shared__ int fmt_s;
    __shared__ int wtot[4];
    __shared__ int Ls;
    if (tid == 0) fmt_s = 0;
    __syncthreads();
    int nz = 0;
    for (int i = tid; i < BB * SS; i += 256)
        if ((i & 3) && mball[i]) nz = 1;
    if (nz) fmt_s = 1;          // benign race: all writers store 1
    __syncthreads();
    const int fmt = fmt_s;      // 1 = byte format

    const int base = tid * 4;
    int v[4];
#pragma unroll
    for (int e = 0; e < 4; ++e) {
        int val = fmt ? (int)mball[(size_t)b * SS + base + e]
                      : ((const int*)mask)[(size_t)b * SS + base + e];
        v[e] = (val == 0) ? 1 : 0;   // keep iff unmasked
    }
    int ts = v[0] + v[1] + v[2] + v[3];

    const int lane = tid & 63, wv = tid >> 6;
    int incl = ts;
#pragma unroll
    for (int d = 1; d < 64; d <<= 1) {
        int t = __shfl_up(incl, d);
        if (lane >= d) incl += t;
    }
    if (lane == 63) wtot[wv] = incl;
    __syncthreads();
    int woff = 0;
    for (int w = 0; w < wv; ++w) woff += wtot[w];
    int run = woff + incl - ts;   // exclusive prefix for this thread's first elem
#pragma unroll
    for (int e = 0; e < 4; ++e) {
        if (v[e]) rmap[(size_t)b * SS + run] = base + e;
        run += v[e];
    }
    __syncthreads();
    if (tid == 0) {
        Ls = wtot[0] + wtot[1] + wtot[2] + wtot[3];
        Larr[b] = Ls;
    }
    __syncthreads();
    for (int j = Ls + tid; j < SS; j += 256) rmap[(size_t)b * SS + j] = 0;
}

// ---------------------------------------------------------------------------
// Fused convert + mask scan. Blocks [0,NCVTB): grid-stride f32->bf16 over 7
// regions (q,k,v inputs + 4 weights). Blocks [NCVTB,NCVTB+BB): mask scan for
// batch (blockIdx.x - NCVTB). The 2 µs scan hides under the BW-bound convert.
// ---------------------------------------------------------------------------
__global__ __launch_bounds__(256) void cvt_scan_kernel(
        const float* __restrict__ q,  u16* __restrict__ dq,
        const float* __restrict__ k,  u16* __restrict__ dk,
        const float* __restrict__ v,  u16* __restrict__ dv,
        const float* __restrict__ w0, u16* __restrict__ dw0,
        const float* __restrict__ w1, u16* __restrict__ dw1,
        const float* __restrict__ w2, u16* __restrict__ dw2,
        const float* __restrict__ w3, u16* __restrict__ dw3,
        const void* mask, int* __restrict__ rmap, int* __restrict__ Larr) {
    if (blockIdx.x >= NCVTB) {
        mask_scan_body(mask, rmap, Larr, blockIdx.x - NCVTB);
        return;
    }
    const int NX = NTOK * HSZ / 8;   // 1048576 units per input
    const int NW = HSZ * HSZ / 8;    // 131072 units per weight
    const int ntot = 3 * NX + 4 * NW;
    int i = blockIdx.x * blockDim.x + threadIdx.x;
    const int stride = NCVTB * 256;
    for (; i < ntot; i += stride) {
        const float* s; u16* d; int j = i;
        if      (j < NX)            { s = q;  d = dq;  }
        else if ((j -= NX) < NX)    { s = k;  d = dk;  }
        else if ((j -= NX) < NX)    { s = v;  d = dv;  }
        else if ((j -= NX) < NW)    { s = w0; d = dw0; }
        else if ((j -= NW) < NW)    { s = w1; d = dw1; }
        else if ((j -= NW) < NW)    { s = w2; d = dw2; }
        else    { j -= NW;            s = w3; d = dw3; }
        f32x4 a = *(const f32x4*)&s[(size_t)j * 8];
        f32x4 b = *(const f32x4*)&s[(size_t)j * 8 + 4];
        union { bf16x8 v8; u16 u[8]; } t;
#pragma unroll
        for (int e = 0; e < 4; ++e) { t.u[e] = bfc(a[e]); t.u[4 + e] = bfc(b[e]); }
        *(bf16x8*)&d[(size_t)j * 8] = t.v8;
    }
}

// ---------------------------------------------------------------------------
// Projection GEMM body: Y = X(bf16) @ W(bf16)^T + b.  BM=BN=128, BK=64,
// 4 waves (2x2), 4x4 frags/wave; both tiles staged via global_load_lds.
// NEW (r16): LDS DOUBLE-BUFFERED with prefetch (T3-minimum 2-phase, the
// pattern proven by r15's attn): issue step t+1's 8 gloads, ds_read+MFMA
// step t, ONE barrier per step. Loads fly during the 128-MFMA compute phase
// instead of being serialized by a vmcnt(0) drain before every compute.
// Rule-#21 XOR swizzle (slot^=(row&7)) on source + read: 0 bank conflicts
// (measured r14).
// MODE 0: Q -> bf16 [B,H,S,D], scaled by (1/8)*log2e  (all 8192 rows)
// MODE 1: K -> bf16 [B,H,Scomp,D]  gather via rmap, compacted output
// MODE 2: V -> bf16 [B,H,D,Scomp]  gather + transpose
// MODE 3: ctx(bf16) @ Wo^T + bo -> f32 [B,S,HS] (d_out)
// ---------------------------------------------------------------------------
template<int MODE>
__device__ __forceinline__ void proj_body(const u16* __restrict__ X,
                                          const u16* __restrict__ W,
                                          const float* __restrict__ bias,
                                          const int* __restrict__ rmap,
                                          const int* __restrict__ Larr,
                                          void* __restrict__ Yv,
                                          u16* Xs0, u16* Ws0,
                                          u16* Xs1, u16* Ws1) {
    const int bm = blockIdx.x;
    const int bn = blockIdx.y;
    const int tid  = threadIdx.x;
    const int wave = tid >> 6;
    const int lane = tid & 63;
    const int l15  = lane & 15;
    const int g    = lane >> 4;
    const int wr   = wave >> 1;
    const int wc   = wave & 1;

    const int b_   = bm >> 3;          // batch (MODE 1/2)
    const int row0 = (bm & 7) * 128;   // compacted row base (MODE 1/2)
    if constexpr (MODE == 1 || MODE == 2) {
        const int L = Larr[b_];
        const int Lpad = ((L + 127) >> 7) << 7;
        if (row0 >= Lpad) return;      // block fully in dead pad region
    }

    f32x4 acc[4][4] = {};

    // staging geometry: tile = 128 rows x 64 cols bf16 = 1024 16B-slots;
    // thread covers 4 slots. slot -> (row = slot>>3, s = slot&7);
    // source column slot = s ^ (row&7)  (XOR involution, rule #21).
    int srow[4], scol[4], xr[4];
#pragma unroll
    for (int i = 0; i < 4; ++i) {
        const int slot = wave * 256 + i * 64 + lane;
        const int r = slot >> 3, s = slot & 7;
        srow[i] = r;
        scol[i] = (s ^ (r & 7)) * 8;   // swizzled source column (shorts)
        if constexpr (MODE == 1 || MODE == 2)
            xr[i] = (b_ << 10) + rmap[(size_t)b_ * SS + row0 + r];
        else
            xr[i] = bm * 128 + r;
    }

    auto stage = [&](u16* Xd, u16* Wd, int k0) {
#pragma unroll
        for (int i = 0; i < 4; ++i) {
            gload16(&X[(size_t)xr[i] * HSZ + k0 + scol[i]], &Xd[(wave * 4 + i) * 512]);
            gload16(&W[(size_t)(bn * 128 + srow[i]) * HSZ + k0 + scol[i]],
                    &Wd[(wave * 4 + i) * 512]);
        }
    };
    auto compute = [&](const u16* Xc, const u16* Wc) {
#pragma unroll
        for (int kk = 0; kk < 2; ++kk) {
            const int cw = ((kk * 4 + g) ^ (l15 & 7)) * 8;
            bf16x8 a[4], bb[4];
#pragma unroll
            for (int m = 0; m < 4; ++m)
                a[m] = *(const bf16x8*)&Xc[(size_t)(wr * 64 + m * 16 + l15) * 64 + cw];
#pragma unroll
            for (int n = 0; n < 4; ++n)
                bb[n] = *(const bf16x8*)&Wc[(size_t)(wc * 64 + n * 16 + l15) * 64 + cw];
#pragma unroll
            for (int m = 0; m < 4; ++m)
#pragma unroll
                for (int n = 0; n < 4; ++n)
                    acc[m][n] = __builtin_amdgcn_mfma_f32_16x16x32_bf16(a[m], bb[n], acc[m][n], 0, 0, 0);
        }
    };

    // prologue + dbuf main loop: one barrier per K-step; prefetch in flight
    // during compute (loads drained by the END-of-step barrier).
    stage(Xs0, Ws0, 0);
    __syncthreads();
    const int NT = HSZ / 64;   // 16
    for (int t = 0; t < NT; ++t) {
        const int p = t & 1;
        if (t + 1 < NT) stage(p ? Xs0 : Xs1, p ? Ws0 : Ws1, (t + 1) * 64);
        compute(p ? Xs1 : Xs0, p ? Ws1 : Ws0);
        __syncthreads();   // all waves done with buf p; prefetch gloads drained
    }

    // ---- epilogue ----
#pragma unroll
    for (int m = 0; m < 4; ++m) {
#pragma unroll
        for (int n = 0; n < 4; ++n) {
            const int o = bn * 128 + wc * 64 + n * 16 + l15;
            const float bvv = bias[o];
            const int h_ = o >> 6, d = o & 63;
#pragma unroll
            for (int r = 0; r < 4; ++r) {
                const int lrow = wr * 64 + m * 16 + g * 4 + r;   // 0..127 in block
                float y = acc[m][n][r] + bvv;
                if constexpr (MODE == 0) {
                    const int nrow = bm * 128 + lrow;
                    int bb_ = nrow >> 10, s = nrow & 1023;
                    ((u16*)Yv)[(((size_t)bb_ * HH + h_) * SS + s) * DD + d] = bfc(y * (0.125f * LOG2E));
                } else if constexpr (MODE == 1) {
                    ((u16*)Yv)[(((size_t)b_ * HH + h_) * SS + row0 + lrow) * DD + d] = bfc(y);
                } else if constexpr (MODE == 2) {
                    ((u16*)Yv)[(((size_t)b_ * HH + h_) * DD + d) * SS + row0 + lrow] = bfc(y);
                } else {
                    const int nrow = bm * 128 + lrow;
                    ((float*)Yv)[(size_t)nrow * HSZ + o] = y;
                }
            }
        }
    }
}

// Fused Q/K/V projection: blockIdx.z selects the projection (packing fills
// CUs through proj<1>/<2>'s ~45% early-exit blocks, removes 2 launch gaps).
__global__ __launch_bounds__(256) void proj_qkv_kernel(
        const u16* __restrict__ qbf, const u16* __restrict__ wqb,
        const float* __restrict__ bq, u16* __restrict__ Qh,
        const u16* __restrict__ kbf, const u16* __restrict__ wkb,
        const float* __restrict__ bk, u16* __restrict__ Kh,
        const u16* __restrict__ vbf, const u16* __restrict__ wvb,
        const float* __restrict__ bv, u16* __restrict__ Vt,
        const int* __restrict__ rmap, const int* __restrict__ Larr) {
    __shared__ u16 Xs0[128 * 64], Ws0[128 * 64];   // 16 KB each
    __shared__ u16 Xs1[128 * 64], Ws1[128 * 64];   // dbuf pair (64 KB total)
    if (blockIdx.z == 0)
        proj_body<0>(qbf, wqb, bq, rmap, Larr, Qh, Xs0, Ws0, Xs1, Ws1);
    else if (blockIdx.z == 1)
        proj_body<1>(kbf, wkb, bk, rmap, Larr, Kh, Xs0, Ws0, Xs1, Ws1);
    else
        proj_body<2>(vbf, wvb, bv, rmap, Larr, Vt, Xs0, Ws0, Xs1, Ws1);
}

__global__ __launch_bounds__(256) void proj_o_kernel(
        const u16* __restrict__ X, const u16* __restrict__ W,
        const float* __restrict__ bias, const int* __restrict__ rmap,
        const int* __restrict__ Larr, float* __restrict__ out) {
    __shared__ u16 Xs0[128 * 64], Ws0[128 * 64];
    __shared__ u16 Xs1[128 * 64], Ws1[128 * 64];
    proj_body<3>(X, W, bias, rmap, Larr, out, Xs0, Ws0, Xs1, Ws1);
}

// ---------------------------------------------------------------------------
// Attention over COMPACTED keys (round-15 proven config, UNCHANGED: K/V
// chunks staged in LDS once per block, dbuf + prefetch, one barrier/chunk;
// XOR involution reads, 0 conflicts; qq=4; swapped QK^T; online softmax with
// defer-max; exp2; tail clamp BEFORE max; s_setprio out per r11).
// ---------------------------------------------------------------------------
__global__ __launch_bounds__(256, 2) void attn_kernel(const u16* __restrict__ Qh,
                                                      const u16* __restrict__ Kh,
                                                      const u16* __restrict__ Vt,
                                                      const int* __restrict__ Larr,
                                                      u16* __restrict__ ctx) {
    const int qt = blockIdx.x;   // 0..3
    const int h  = blockIdx.y;   // 0..15
    const int b  = blockIdx.z;   // 0..7
    const int bh = b * HH + h;

    const int tid  = threadIdx.x;
    const int wave = tid >> 6;
    const int lane = tid & 63;
    const int l15  = lane & 15;
    const int g    = lane >> 4;
    const int qw0  = qt * 256 + wave * 64;   // first query of this wave

    __shared__ u16 Ks[2][64 * 64];           // 8 KB x2 (dbuf), XOR-swizzled rows
    __shared__ u16 Vs[2][64 * 64];           // 8 KB x2
    __shared__ u16 Pw[4][2][16][72];         // 18 KB; stride 72 -> 2-way (free)

    const u16* Qb = Qh + ((size_t)bh * SS + qw0) * DD;
    const u16* Kb = Kh + (size_t)bh * SS * DD;
    const u16* Vb = Vt + (size_t)bh * DD * SS;

    const int L = Larr[b];
    const int nchunks = (L + 63) >> 6;   // 64-key chunks; K/V rows < ceil128(L) valid

    // Q fragments: qf[qq][half] = Q[qw0+qq*16+l15][half*32 + g*8 ..+8]
    bf16x8 qf[4][2];
#pragma unroll
    for (int qq = 0; qq < 4; ++qq)
#pragma unroll
        for (int hh = 0; hh < 2; ++hh)
            qf[qq][hh] = *(const bf16x8*)&Qb[(size_t)(qq * 16 + l15) * DD + hh * 32 + g * 8];

    f32x4 o[4][4] = {};                      // [qq][dt]; query = qq*16+g*4+r, d = dt*16+l15
    float mrun[4] = { -3e38f, -3e38f, -3e38f, -3e38f };
    float lrun[4] = { 0.0f, 0.0f, 0.0f, 0.0f };

    // stage one 64x64 chunk of K and V into LDS parity p (512 slots each;
    // thread covers slots tid and tid+256). LDS dest linear; SOURCE column
    // pre-swizzled with the rule-#21 involution.
    auto stage = [&](u16* Kp, u16* Vp, int c0) {
#pragma unroll
        for (int i = 0; i < 2; ++i) {
            const int slot = i * 256 + tid;             // 0..511
            const int r  = slot >> 3;                   // tile row 0..63
            const int cs = ((slot & 7) ^ (r & 7)) * 8;  // swizzled src col (shorts)
            u16* dstK = Kp + (size_t)(i * 256 + wave * 64) * 8;
            u16* dstV = Vp + (size_t)(i * 256 + wave * 64) * 8;
            gload16(&Kb[(size_t)(c0 + r) * DD + cs], dstK);   // K rows = keys
            gload16(&Vb[(size_t)r * SS + c0 + cs],   dstV);   // V rows = d
        }
    };
    // frag reads through the same involution (row&7 == l15&7; kt/dt*16 = 0 mod 8)
    auto loadKfrag = [&](const u16* Kp, bf16x8 (&kf)[8]) {
#pragma unroll
        for (int kt = 0; kt < 4; ++kt)
#pragma unroll
            for (int hh = 0; hh < 2; ++hh) {
                const int cw = ((hh * 4 + g) ^ (l15 & 7)) * 8;
                kf[kt * 2 + hh] = *(const bf16x8*)&Kp[(size_t)(kt * 16 + l15) * 64 + cw];
            }
    };
    auto loadVfrag = [&](const u16* Vp, bf16x8 (&vf)[8]) {
#pragma unroll
        for (int dt = 0; dt < 4; ++dt)
#pragma unroll
            for (int kh = 0; kh < 2; ++kh) {
                const int cw = ((kh * 4 + g) ^ (l15 & 7)) * 8;
                vf[dt * 2 + kh] = *(const bf16x8*)&Vp[(size_t)(dt * 16 + l15) * 64 + cw];
            }
    };

    auto process = [&](const bf16x8 (&kf)[8], const bf16x8 (&vf)[8], int c0) {
#pragma unroll
        for (int qq = 0; qq < 4; ++qq) {
            // QK^T (swapped): s[kt][r] = score2(key c0+kt*16+g*4+r, query qw0+qq*16+l15)
            f32x4 s[4];
#pragma unroll
            for (int kt = 0; kt < 4; ++kt) {
                f32x4 a = {};
                a = __builtin_amdgcn_mfma_f32_16x16x32_bf16(kf[kt * 2 + 0], qf[qq][0], a, 0, 0, 0);
                a = __builtin_amdgcn_mfma_f32_16x16x32_bf16(kf[kt * 2 + 1], qf[qq][1], a, 0, 0, 0);
                s[kt] = a;
            }
            // tail clamp BEFORE the max (pad keys -> -3e38 -> P=0 exactly)
            if (c0 + 64 > L) {
#pragma unroll
                for (int kt = 0; kt < 4; ++kt) {
                    const int kid = c0 + kt * 16 + g * 4;
#pragma unroll
                    for (int r = 0; r < 4; ++r)
                        s[kt][r] = (kid + r < L) ? s[kt][r] : -3e38f;
                }
            }
            // chunk max (tree; per query l15)
            float pmk[4];
#pragma unroll
            for (int kt = 0; kt < 4; ++kt)
                pmk[kt] = fmaxf(fmaxf(s[kt][0], s[kt][1]), fmaxf(s[kt][2], s[kt][3]));
            float pm = fmaxf(fmaxf(pmk[0], pmk[1]), fmaxf(pmk[2], pmk[3]));
            pm = fmaxf(pm, __shfl_xor(pm, 16));
            pm = fmaxf(pm, __shfl_xor(pm, 32));

            // defer-max: rescale only when max grows past 8*log2e (wave-uniform)
            if (!__all(pm <= mrun[qq] + 11.5416f)) {
                float sc = exp2fast(mrun[qq] - pm);   // first chunk: exp2(-huge)=0
                mrun[qq] = pm;
                lrun[qq] *= sc;
                float f0 = __shfl(sc, g * 4 + 0);
                float f1 = __shfl(sc, g * 4 + 1);
                float f2 = __shfl(sc, g * 4 + 2);
                float f3 = __shfl(sc, g * 4 + 3);
#pragma unroll
                for (int dt = 0; dt < 4; ++dt) {
                    o[qq][dt][0] *= f0; o[qq][dt][1] *= f1;
                    o[qq][dt][2] *= f2; o[qq][dt][3] *= f3;
                }
            }

            // P~ = exp2(s - mrun) -> bf16 LDS (transpose to query-major), local sum
            float ls = 0.0f;
#pragma unroll
            for (int kt = 0; kt < 4; ++kt) {
                union { u16x4 v; u16 u[4]; } pv;
#pragma unroll
                for (int r = 0; r < 4; ++r) {
                    float e = exp2fast(s[kt][r] - mrun[qq]);
                    ls += e;
                    pv.u[r] = bfc(e);
                }
                *(u16x4*)&Pw[wave][qq & 1][l15][kt * 16 + g * 4] = pv.v;
            }
            ls += __shfl_xor(ls, 16);
            ls += __shfl_xor(ls, 32);
            lrun[qq] += ls;

            // PV: O[q][d] += P~ . V
#pragma unroll
            for (int kh = 0; kh < 2; ++kh) {
                bf16x8 pa = *(const bf16x8*)&Pw[wave][qq & 1][l15][kh * 32 + g * 8];
#pragma unroll
                for (int dt = 0; dt < 4; ++dt)
                    o[qq][dt] = __builtin_amdgcn_mfma_f32_16x16x32_bf16(pa, vf[dt * 2 + kh], o[qq][dt], 0, 0, 0);
            }
        }
    };

    // main loop: prefetch c+1 while computing c; one barrier per chunk.
    stage(&Ks[0][0], &Vs[0][0], 0);
    __syncthreads();
    for (int c = 0; c < nchunks; ++c) {
        const int p = c & 1;
        if (c + 1 < nchunks) stage(&Ks[p ^ 1][0], &Vs[p ^ 1][0], (c + 1) * 64);
        bf16x8 kf[8], vf[8];
        loadKfrag(&Ks[p][0], kf);
        loadVfrag(&Vs[p][0], vf);
        process(kf, vf, c * 64);
        __syncthreads();   // drains prefetch gloads; all waves done with buf p
    }

    // ---- epilogue: normalize per query, write ctx bf16 ----
#pragma unroll
    for (int qq = 0; qq < 4; ++qq) {
        float inv = 1.0f / lrun[qq];           // valid for query l15 (uniform over g)
        float i0 = __shfl(inv, g * 4 + 0);
        float i1 = __shfl(inv, g * 4 + 1);
        float i2 = __shfl(inv, g * 4 + 2);
        float i3 = __shfl(inv, g * 4 + 3);
#pragma unroll
        for (int dt = 0; dt < 4; ++dt) {
            const int col = h * DD + dt * 16 + l15;
            const int qr  = b * SS + qw0 + qq * 16 + g * 4;
            ctx[(size_t)(qr + 0) * HSZ + col] = bfc(o[qq][dt][0] * i0);
            ctx[(size_t)(qr + 1) * HSZ + col] = bfc(o[qq][dt][1] * i1);
            ctx[(size_t)(qr + 2) * HSZ + col] = bfc(o[qq][dt][2] * i2);
            ctx[(size_t)(qr + 3) * HSZ + col] = bfc(o[qq][dt][3] * i3);
        }
    }
}

// ---------------------------------------------------------------------------
extern "C" void kernel_launch(void* const* d_in, const int* in_sizes, int n_in,
                              void* d_out, int out_size, void* d_ws, size_t ws_size,
                              hipStream_t stream) {
    const float* v    = (const float*)d_in[0];
    const float* k    = (const float*)d_in[1];
    const float* q    = (const float*)d_in[2];
    const void*  mask = d_in[3];
    const float* Wq = (const float*)d_in[4];
    const float* bq = (const float*)d_in[5];
    const float* Wk = (const float*)d_in[6];
    const float* bk = (const float*)d_in[7];
    const float* Wv = (const float*)d_in[8];
    const float* bv = (const float*)d_in[9];
    const float* Wo = (const float*)d_in[10];
    const float* bo = (const float*)d_in[11];

    // d_out (32 MB f32, fully rewritten by the final proj_o) doubles as
    // scratch for the q/k bf16 staging buffers before proj_o runs.
    u16* qbf = (u16*)d_out;                         // 16 MB (dead after proj z=0)
    u16* kbf = qbf + (size_t)NTOK * HSZ;            // 16 MB (dead after proj z=1)

    char* ws = (char*)d_ws;
    int*   rmap = (int*)ws;                         // 32 KB
    int*   Larr = (int*)(ws + 32768);               // 32 B
    u16*   wqb  = (u16*)(ws + 65536);               // 2 MB each
    u16*   wkb  = wqb + (size_t)HSZ * HSZ;
    u16*   wvb  = wkb + (size_t)HSZ * HSZ;
    u16*   wob  = wvb + (size_t)HSZ * HSZ;
    u16*   vbf  = wob + (size_t)HSZ * HSZ;          // 16 MB (v bf16; ctx overlays)
    u16*   Qh   = vbf + (size_t)NTOK * HSZ;         // 16 MB each
    u16*   Kh   = Qh + (size_t)NTOK * HSZ;
    u16*   Vt   = Kh + (size_t)NTOK * HSZ;
    u16*   ctx  = vbf;                              // reuse (free after proj z=2)

    cvt_scan_kernel<<<NCVTB + BB, 256, 0, stream>>>(q, qbf, k, kbf, v, vbf,
                                                    Wq, wqb, Wk, wkb, Wv, wvb, Wo, wob,
                                                    mask, rmap, Larr);

    dim3 pgrid(NTOK / 128, HSZ / 128, 3);   // (64, 8, 3)
    proj_qkv_kernel<<<pgrid, 256, 0, stream>>>(qbf, wqb, bq, Qh,
                                               kbf, wkb, bk, Kh,
                                               vbf, wvb, bv, Vt,
                                               rmap, Larr);

    dim3 agrid(SS / 256, HH, BB);           // (4, 16, 8)
    attn_kernel<<<agrid, 256, 0, stream>>>(Qh, Kh, Vt, Larr, ctx);

    dim3 ogrid(NTOK / 128, HSZ / 128);      // (64, 8)
    proj_o_kernel<<<ogrid, 256, 0, stream>>>(ctx, wob, bo, rmap, Larr, (float*)d_out);
}